// Round 17
// baseline (268.414 us; speedup 1.0000x reference)
//
#include <hip/hip_runtime.h>

#define F1 33

// cos(2*pi*m/64); sin(2*pi*m/64) = TWD[(m+48)&63]
constexpr float TWD[64] = {
   1.00000000f,  0.99518473f,  0.98078528f,  0.95694034f,
   0.92387953f,  0.88192126f,  0.83146961f,  0.77301045f,
   0.70710678f,  0.63439328f,  0.55557023f,  0.47139674f,
   0.38268343f,  0.29028468f,  0.19509032f,  0.09801714f,
   0.00000000f, -0.09801714f, -0.19509032f, -0.29028468f,
  -0.38268343f, -0.47139674f, -0.55557023f, -0.63439328f,
  -0.70710678f, -0.77301045f, -0.83146961f, -0.88192126f,
  -0.92387953f, -0.95694034f, -0.98078528f, -0.99518473f,
  -1.00000000f, -0.99518473f, -0.98078528f, -0.95694034f,
  -0.92387953f, -0.88192126f, -0.83146961f, -0.77301045f,
  -0.70710678f, -0.63439328f, -0.55557023f, -0.47139674f,
  -0.38268343f, -0.29028468f, -0.19509032f, -0.09801714f,
   0.00000000f,  0.09801714f,  0.19509032f,  0.29028468f,
   0.38268343f,  0.47139674f,  0.55557023f,  0.63439328f,
   0.70710678f,  0.77301045f,  0.83146961f,  0.88192126f,
   0.92387953f,  0.95694034f,  0.98078528f,  0.99518473f,
};

#define NROWS 524288   // 16384 units * 32 a-rows

// ------- K0: sort modes by k (tie: original l); bit24 = run-end; invperm ----
__global__ __launch_bounds__(256) void k_sort(const int* __restrict__ mask,
                                              int* __restrict__ sorted,
                                              int* __restrict__ invperm) {
  __shared__ int ks[256];
  __shared__ int sv[256];
  __shared__ int skey[256];
  int t = threadIdx.x;
  int mi = mask[t];
  int j = mi / F1;
  int k = mi - j * F1;
  ks[t] = k;
  __syncthreads();
  int mykey = (k << 8) | t;
  int rank = 0;
  for (int l2 = 0; l2 < 256; ++l2)
    rank += (((ks[l2] << 8) | l2) < mykey);
  sv[rank]   = (k << 16) | (j << 8) | t;
  skey[rank] = k;
  invperm[t] = rank;                 // original index t -> sorted position
  __syncthreads();
  int isend = (t == 255) || (skey[t] != skey[t + 1]);
  sorted[t] = sv[t] | (isend << 24);
}

// ---------------- K1 v3: forward, 2-level DIF stage A (R9 version) ----------
__global__ __launch_bounds__(256, 4) void k_fwd(const float* __restrict__ x,
                                                const int* __restrict__ sorted,
                                                float2* __restrict__ xm) {
  __shared__ float2 rbuf[128][35];   // [row][k], pad 35
  __shared__ float2 cs32[32];        // (cos,sin)(2*pi*m/32)
  int t = threadIdx.x;
  if (t < 32) cs32[t] = make_float2(TWD[(2 * t) & 63], TWD[(2 * t + 48) & 63]);

  int rl  = t >> 1;
  int par = t & 1;
  size_t row = (size_t)blockIdx.x * 128 + rl;
  const float4* xp = (const float4*)(x + row * 64);

  float f[32];
#pragma unroll
  for (int q = 0; q < 16; ++q) {
    float4 v = xp[q];
    f[2 * q + 0] = par ? v.y : v.x;
    f[2 * q + 1] = par ? v.w : v.z;
  }

  float s1v[16], d1v[16];
#pragma unroll
  for (int m = 0; m < 16; ++m) {
    s1v[m] = f[m] + f[m + 16];
    d1v[m] = f[m] - f[m + 16];
  }
  float s2v[8], d2v[8];
#pragma unroll
  for (int m = 0; m < 8; ++m) {
    s2v[m] = s1v[m] + s1v[m + 8];
    d2v[m] = s1v[m] - s1v[m + 8];
  }
  float mR[17], mI[17];
#pragma unroll
  for (int j = 0; j < 17; ++j) { mR[j] = 0.f; mI[j] = 0.f; }
#pragma unroll
  for (int m = 0; m < 8; ++m) {
#pragma unroll
    for (int tq = 0; tq < 5; ++tq) {
      const int j = 4 * tq;
      const int a = (2 * j * m) & 63;        // compile-time
      const float c  = TWD[a];
      const float sn = TWD[(a + 48) & 63];
      if (c  != 0.0f) mR[j] = fmaf(s2v[m],  c,  mR[j]);
      if (sn != 0.0f) mI[j] = fmaf(s2v[m], -sn, mI[j]);
    }
  }
#pragma unroll
  for (int m = 0; m < 8; ++m) {
#pragma unroll
    for (int tq = 0; tq < 4; ++tq) {
      const int j = 4 * tq + 2;
      const int a = (2 * j * m) & 63;
      const float c  = TWD[a];
      const float sn = TWD[(a + 48) & 63];
      if (c  != 0.0f) mR[j] = fmaf(d2v[m],  c,  mR[j]);
      if (sn != 0.0f) mI[j] = fmaf(d2v[m], -sn, mI[j]);
    }
  }
#pragma unroll
  for (int m = 0; m < 16; ++m) {
#pragma unroll
    for (int r = 0; r < 8; ++r) {
      const int j = 2 * r + 1;
      const int a = (2 * j * m) & 63;
      const float c  = TWD[a];
      const float sn = TWD[(a + 48) & 63];
      if (c  != 0.0f) mR[j] = fmaf(d1v[m],  c,  mR[j]);
      if (sn != 0.0f) mI[j] = fmaf(d1v[m], -sn, mI[j]);
    }
  }

  float oR[17], oI[17];
#pragma unroll
  for (int j = 0; j < 17; ++j) {
    oR[j] = __shfl_xor(mR[j], 1, 64);
    oI[j] = __shfl_xor(mI[j], 1, 64);
  }

  if (par == 0) {
#pragma unroll
    for (int k = 0; k <= 16; ++k) {
      const float wr = TWD[k];
      const float s  = TWD[(k + 48) & 63];
      float XR = mR[k];
      float XI = mI[k];
      if (s  != 0.0f) { XR = fmaf( s, oI[k], XR); XI = fmaf(-s, oR[k], XI); }
      if (wr != 0.0f) { XR = fmaf(wr, oR[k], XR); XI = fmaf(wr, oI[k], XI); }
      rbuf[rl][k] = make_float2(XR, XI);
    }
  } else {
#pragma unroll
    for (int k = 17; k <= 31; ++k) {
      const float wr = TWD[k];
      const float s  = TWD[(k + 48) & 63];
      const int p = 32 - k;
      float XR = oR[p];
      float XI = -oI[p];
      if (s  != 0.0f) { XR = fmaf(-s, mI[p], XR); XI = fmaf(-s, mR[p], XI); }
      if (wr != 0.0f) { XR = fmaf(wr, mR[p], XR); XI = fmaf(-wr, mI[p], XI); }
      rbuf[rl][k] = make_float2(XR, XI);
    }
    rbuf[rl][32] = make_float2(oR[0] - mR[0], 0.0f);
  }
  __syncthreads();

  int e = sorted[t];
  int k = (e >> 16) & 63, j = (e >> 8) & 255, l = e & 255;
  float2 acc[4];
#pragma unroll
  for (int u = 0; u < 4; ++u) acc[u] = make_float2(0.f, 0.f);

#pragma unroll 4
  for (int s0 = 0; s0 < 32; ++s0) {
    float2 cs = cs32[(j * s0) & 31];
#pragma unroll
    for (int u = 0; u < 4; ++u) {
      float2 rv = rbuf[u * 32 + s0][k];
      acc[u].x = fmaf(rv.x, cs.x, fmaf(rv.y,  cs.y, acc[u].x));
      acc[u].y = fmaf(rv.y, cs.x, fmaf(-rv.x, cs.y, acc[u].y));
    }
  }
  size_t ub = (size_t)blockIdx.x * 4;
#pragma unroll
  for (int u = 0; u < 4; ++u)
    xm[(ub + u) * 256 + l] = acc[u];
}

// ---------------- K2 v6: l-split x2 -> grid 512, 2+ blocks/CU ----------------
// 64 l-groups of 4 (was 32 of 8): per-block tiles halve (LDS ~25 KB), no
// operand duplication (l partitions exactly; FETCH unchanged). Lane remap
// and per-output i-accumulation order identical to v5 -> bit-identical om.
__global__ __launch_bounds__(512, 4) void k_mix(const float2* __restrict__ xm,
                                                const float* __restrict__ wr,
                                                const float* __restrict__ wi,
                                                float2* __restrict__ om) {
  __shared__ float4 Asm4[8][2][33];  // 8.4 KB   [i][p][b]
  __shared__ float4 Wsm4[8][65][2];  // 16.6 KB  [i][o(pad)][p]
  int t = threadIdx.x;
  int h  = blockIdx.x >> 6;
  int lb = (blockIdx.x & 63) * 4;

  int w    = t >> 6;        // wave id (0..7) -> o block of 8
  int lane = t & 63;
  int b_lo = lane >> 2;     // 16 values
  int o_lo = lane & 3;      // 4 values

  float4 acc[2][2][2];
#pragma unroll
  for (int brp = 0; brp < 2; ++brp)
#pragma unroll
    for (int orp = 0; orp < 2; ++orp)
#pragma unroll
      for (int p = 0; p < 2; ++p)
        acc[brp][orp][p] = make_float4(0.f, 0.f, 0.f, 0.f);

  for (int ic = 0; ic < 8; ++ic) {
    __syncthreads();
    // stage A: 512 chunks: c = t -> (p, i, b), one float4 per thread
    {
      int c = t;
      int p = c & 1, ii = (c >> 1) & 7, b = c >> 4;
      const float4* src = (const float4*)(xm +
          (size_t)(((b * 8 + h) * 64) + ic * 8 + ii) * 256 + lb + 2 * p);
      Asm4[ii][p][b] = *src;
    }
    // stage W: 512 chunks: c = t -> (o, i), 2 dst float4 per thread
    {
      int c = t;
      int oo = c & 63, ii = c >> 6;
      size_t gidx = (size_t)((h * 64 + ic * 8 + ii) * 64 + oo) * 256 + lb;
      float4 vr = *(const float4*)(wr + gidx);
      float4 vi = *(const float4*)(wi + gidx);
      Wsm4[ii][oo][0] = make_float4(vr.x, vi.x, vr.y, vi.y);
      Wsm4[ii][oo][1] = make_float4(vr.z, vi.z, vr.w, vi.w);
    }
    __syncthreads();
#pragma unroll
    for (int i = 0; i < 8; ++i) {
      float4 av[2][2], wv[2][2];
#pragma unroll
      for (int brp = 0; brp < 2; ++brp)
#pragma unroll
        for (int p = 0; p < 2; ++p)
          av[brp][p] = Asm4[i][p][brp * 16 + b_lo];       // 16 addrs/instr
#pragma unroll
      for (int orp = 0; orp < 2; ++orp)
#pragma unroll
        for (int p = 0; p < 2; ++p)
          wv[orp][p] = Wsm4[i][w * 8 + orp * 4 + o_lo][p]; // 4 addrs/instr
#pragma unroll
      for (int brp = 0; brp < 2; ++brp)
#pragma unroll
        for (int orp = 0; orp < 2; ++orp)
#pragma unroll
          for (int p = 0; p < 2; ++p) {
            float4 A = av[brp][p], W = wv[orp][p];
            float4& C = acc[brp][orp][p];
            C.x = fmaf(A.x, W.x, fmaf(-A.y, W.y, C.x));
            C.y = fmaf(A.x, W.y, fmaf( A.y, W.x, C.y));
            C.z = fmaf(A.z, W.z, fmaf(-A.w, W.w, C.z));
            C.w = fmaf(A.z, W.w, fmaf( A.w, W.z, C.w));
          }
    }
  }
#pragma unroll
  for (int brp = 0; brp < 2; ++brp)
#pragma unroll
    for (int orp = 0; orp < 2; ++orp)
#pragma unroll
      for (int p = 0; p < 2; ++p) {
        int b = brp * 16 + b_lo;
        int o = w * 8 + orp * 4 + o_lo;
        *(float4*)(om + (size_t)(((b * 8 + h) * 64) + o) * 256 + lb + 2 * p)
            = acc[brp][orp][p];
      }
}

// ---------------- K3a: mode sum -> T[k][unit*32+a] (coalesced planes) -------
// Per-thread 64-bit `seen` bitmask marks flushed k planes; absent ones
// zero-filled by the SAME thread afterwards.
__global__ __launch_bounds__(256, 4) void k_inv_a(const float2* __restrict__ om,
                                                  const int* __restrict__ sorted,
                                                  const int* __restrict__ invperm,
                                                  float* __restrict__ T) {
  __shared__ float4 om16s[16 * 128];  // 32.8 KB, sorted-order pairs
  __shared__ float2 cs32[32];
  __shared__ int4   smodes4[64];
  int t = threadIdx.x;
  size_t ub = (size_t)blockIdx.x * 16;

  {
    int pos = invperm[t];
    float2* dst = (float2*)om16s;
    const float2* omg = om + ub * 256;
#pragma unroll
    for (int u = 0; u < 16; ++u)
      dst[u * 256 + pos] = omg[u * 256 + t];
  }
  if (t < 32) cs32[t] = make_float2(TWD[(2 * t) & 63], TWD[(2 * t + 48) & 63]);
  if (t < 64) smodes4[t] = ((const int4*)sorted)[t];
  __syncthreads();

  int up = t >> 5;          // unit-pair 0..7
  int a  = t & 31;
  int u0 = up * 2, u1 = u0 + 1;
  float g0 = 0.f, g1 = 0.f;
  long long seen = 0;       // 64-bit: shift by k (0..32) well-defined

#define PROC2(EV, R0, I0, R1, I1)                                             \
  do {                                                                        \
    int e_ = (EV);                                                            \
    int j_ = (e_ >> 8) & 255;                                                 \
    float2 cs_ = cs32[(j_ * a) & 31];                                         \
    g0 = fmaf((R0), cs_.x, g0); g0 = fmaf(-(I0), cs_.y, g0);                  \
    g1 = fmaf((R1), cs_.x, g1); g1 = fmaf(-(I1), cs_.y, g1);                  \
    if (e_ & (1 << 24)) {                                                     \
      int k_ = (e_ >> 16) & 63;                                               \
      seen |= 1ll << k_;                                                      \
      T[(size_t)k_ * NROWS + (ub + u0) * 32 + a] = g0;                        \
      T[(size_t)k_ * NROWS + (ub + u1) * 32 + a] = g1;                        \
      g0 = 0.f; g1 = 0.f;                                                     \
    }                                                                         \
  } while (0)

#pragma unroll 2
  for (int q = 0; q < 64; ++q) {
    int4   ee  = smodes4[q];
    float4 oA0 = om16s[u0 * 128 + 2 * q + 0];
    float4 oB0 = om16s[u0 * 128 + 2 * q + 1];
    float4 oA1 = om16s[u1 * 128 + 2 * q + 0];
    float4 oB1 = om16s[u1 * 128 + 2 * q + 1];
    PROC2(ee.x, oA0.x, oA0.y, oA1.x, oA1.y);
    PROC2(ee.y, oA0.z, oA0.w, oA1.z, oA1.w);
    PROC2(ee.z, oB0.x, oB0.y, oB1.x, oB1.y);
    PROC2(ee.w, oB0.z, oB0.w, oB1.z, oB1.w);
  }
#undef PROC2

#pragma unroll
  for (int k = 0; k < 33; ++k)
    if (!((seen >> k) & 1)) {
      T[(size_t)k * NROWS + (ub + u0) * 32 + a] = 0.f;
      T[(size_t)k * NROWS + (ub + u1) * 32 + a] = 0.f;
    }
}

// ---------------- K3b: exact compile-time cosine constants -------------------
template <int SG>
__device__ __forceinline__ void inv_b_body(const float (*T8)[34], int r,
                                           float* __restrict__ y, size_t Rb) {
  float acc[16];
  {
    float t0 = T8[r][0];
#pragma unroll
    for (int o = 0; o < 16; ++o)
      acc[o] = t0 * (1.0f / 2048.0f);          // k=0: cos=1
  }
#pragma unroll
  for (int k = 1; k < 33; ++k) {
    float tk = T8[r][k];
#pragma unroll
    for (int o = 0; o < 16; ++o) {
      const float C = ((k == 32) ? (1.0f / 2048.0f) : (2.0f / 2048.0f))
                    * TWD[(k * (SG * 16 + o)) & 63];   // compile-time literal
      if (C != 0.0f) acc[o] = fmaf(tk, C, acc[o]);
    }
  }
  float* yp = y + (Rb + r) * 64 + SG * 16;
#pragma unroll
  for (int q = 0; q < 4; ++q)
    *(float4*)(yp + 4 * q) = make_float4(acc[4 * q + 0], acc[4 * q + 1],
                                         acc[4 * q + 2], acc[4 * q + 3]);
}

__global__ __launch_bounds__(256, 4) void k_inv_b(const float* __restrict__ T,
                                                  float* __restrict__ y) {
  __shared__ float T8[64][34];
  int t = threadIdx.x;
  size_t Rb = (size_t)blockIdx.x * 64;

#pragma unroll
  for (int q = 0; q < 9; ++q) {
    int c = t + 256 * q;
    if (c < 2112) {
      int kq = c >> 6, r = c & 63;
      T8[r][kq] = T[(size_t)kq * NROWS + Rb + r];   // coalesced 256B runs
    }
  }
  __syncthreads();

  int wv = t >> 6;          // wave-uniform sg
  int r  = t & 63;
  if      (wv == 0) inv_b_body<0>(T8, r, y, Rb);
  else if (wv == 1) inv_b_body<1>(T8, r, y, Rb);
  else if (wv == 2) inv_b_body<2>(T8, r, y, Rb);
  else              inv_b_body<3>(T8, r, y, Rb);
}

// ---------------- K3 v7 fallback (if ws too small): R9 version --------------
__global__ __launch_bounds__(512, 4) void k_inv(const float2* __restrict__ om,
                                                const int* __restrict__ sorted,
                                                const int* __restrict__ invperm,
                                                float* __restrict__ y) {
  __shared__ float4 om8s[8 * 128];
  __shared__ float  c2s[33][64];
  __shared__ float2 cs32[32];
  __shared__ int4   smodes4[64];
  int t = threadIdx.x;
  size_t ub = (size_t)blockIdx.x * 8;

  {
    int l  = t & 255;
    int u0 = t >> 8;
    int pos = invperm[l];
    float2* dst = (float2*)om8s;
    const float2* omg = om + ub * 256;
#pragma unroll
    for (int q = 0; q < 4; ++q) {
      int u = u0 + 2 * q;
      dst[u * 256 + pos] = omg[u * 256 + l];
    }
  }
#pragma unroll
  for (int q = 0; q < 5; ++q) {
    int idx = t + 512 * q;
    if (idx < 2112) {
      int k = idx >> 6, s1 = idx & 63;
      float w = (k == 0 || k == 32) ? (1.0f / 2048.0f) : (2.0f / 2048.0f);
      c2s[k][s1] = w * TWD[(k * s1) & 63];
    }
  }
  if (t < 32) cs32[t] = make_float2(TWD[(2 * t) & 63], TWD[(2 * t + 48) & 63]);
  if (t < 64) smodes4[t] = ((const int4*)sorted)[t];
  __syncthreads();

  int u    = t >> 6;
  int a    = (t >> 1) & 31;
  int half = t & 1;

  float4 a0 = make_float4(0.f,0.f,0.f,0.f), a1 = a0, a2 = a0, a3 = a0;
  float4 a4 = a0, a5 = a0, a6 = a0, a7 = a0;
  float g = 0.f;

#define SPREAD(KK)                                                            \
  do {                                                                        \
    const float4* crow = (const float4*)&c2s[(KK)][half * 32];                \
    float4 c;                                                                 \
    c = crow[0]; a0.x=fmaf(g,c.x,a0.x); a0.y=fmaf(g,c.y,a0.y); a0.z=fmaf(g,c.z,a0.z); a0.w=fmaf(g,c.w,a0.w); \
    c = crow[1]; a1.x=fmaf(g,c.x,a1.x); a1.y=fmaf(g,c.y,a1.y); a1.z=fmaf(g,c.z,a1.z); a1.w=fmaf(g,c.w,a1.w); \
    c = crow[2]; a2.x=fmaf(g,c.x,a2.x); a2.y=fmaf(g,c.y,a2.y); a2.z=fmaf(g,c.z,a2.z); a2.w=fmaf(g,c.w,a2.w); \
    c = crow[3]; a3.x=fmaf(g,c.x,a3.x); a3.y=fmaf(g,c.y,a3.y); a3.z=fmaf(g,c.z,a3.z); a3.w=fmaf(g,c.w,a3.w); \
    c = crow[4]; a4.x=fmaf(g,c.x,a4.x); a4.y=fmaf(g,c.y,a4.y); a4.z=fmaf(g,c.z,a4.z); a4.w=fmaf(g,c.w,a4.w); \
    c = crow[5]; a5.x=fmaf(g,c.x,a5.x); a5.y=fmaf(g,c.y,a5.y); a5.z=fmaf(g,c.z,a5.z); a5.w=fmaf(g,c.w,a5.w); \
    c = crow[6]; a6.x=fmaf(g,c.x,a6.x); a6.y=fmaf(g,c.y,a6.y); a6.z=fmaf(g,c.z,a6.z); a6.w=fmaf(g,c.w,a6.w); \
    c = crow[7]; a7.x=fmaf(g,c.x,a7.x); a7.y=fmaf(g,c.y,a7.y); a7.z=fmaf(g,c.z,a7.z); a7.w=fmaf(g,c.w,a7.w); \
    g = 0.f;                                                                  \
  } while (0)

#define PROC(EV, OVR, OVI)                                                    \
  do {                                                                        \
    int e_ = (EV);                                                            \
    int j_ = (e_ >> 8) & 255;                                                 \
    float2 cs_ = cs32[(j_ * a) & 31];                                         \
    g = fmaf((OVR), cs_.x, g);                                                \
    g = fmaf(-(OVI), cs_.y, g);                                               \
    if (e_ & (1 << 24)) SPREAD((e_ >> 16) & 63);                              \
  } while (0)

#pragma unroll 2
  for (int q = 0; q < 64; ++q) {
    int4   ee = smodes4[q];
    float4 oA = om8s[u * 128 + 2 * q + 0];
    float4 oB = om8s[u * 128 + 2 * q + 1];
    PROC(ee.x, oA.x, oA.y);
    PROC(ee.y, oA.z, oA.w);
    PROC(ee.z, oB.x, oB.y);
    PROC(ee.w, oB.z, oB.w);
  }
#undef PROC
#undef SPREAD

  float4* yp = (float4*)(y + (ub + u) * 2048 + a * 64 + half * 32);
  yp[0] = a0; yp[1] = a1; yp[2] = a2; yp[3] = a3;
  yp[4] = a4; yp[5] = a5; yp[6] = a6; yp[7] = a7;
}

extern "C" void kernel_launch(void* const* d_in, const int* in_sizes, int n_in,
                              void* d_out, int out_size, void* d_ws, size_t ws_size,
                              hipStream_t stream) {
  const float* x    = (const float*)d_in[0];
  const float* wre  = (const float*)d_in[1];
  const float* wim  = (const float*)d_in[2];
  const int*   mask = (const int*)d_in[3];

  float*  y  = (float*)d_out;
  float2* xm = (float2*)d_out;                        // scratch: dead before y written
  float2* omp = (float2*)d_ws;                        // 33.55 MB
  char* base = (char*)d_ws;
  int*  sorted  = (int*)(base + 33554432);            // 1 KB (16B-aligned)
  int*  invperm = (int*)(base + 33555456);            // 1 KB
  float* T      = (float*)(base + 33556480);          // 69.2 MB (if available)
  const size_t ws_needed = 33556480ull + (size_t)33 * NROWS * 4;

  k_sort<<<1, 256, 0, stream>>>(mask, sorted, invperm);
  k_fwd <<<4096, 256, 0, stream>>>(x, sorted, xm);
  k_mix <<<512, 512, 0, stream>>>(xm, wre, wim, omp);
  if (ws_size >= ws_needed) {
    k_inv_a<<<1024, 256, 0, stream>>>(omp, sorted, invperm, T);
    k_inv_b<<<8192, 256, 0, stream>>>(T, y);
  } else {
    k_inv<<<2048, 512, 0, stream>>>(omp, sorted, invperm, y);
  }
}

// Round 18
// 238.339 us; speedup vs baseline: 1.1262x; 1.1262x over previous
//
#include <hip/hip_runtime.h>

#define F1 33

// cos(2*pi*m/64); sin(2*pi*m/64) = TWD[(m+48)&63]
constexpr float TWD[64] = {
   1.00000000f,  0.99518473f,  0.98078528f,  0.95694034f,
   0.92387953f,  0.88192126f,  0.83146961f,  0.77301045f,
   0.70710678f,  0.63439328f,  0.55557023f,  0.47139674f,
   0.38268343f,  0.29028468f,  0.19509032f,  0.09801714f,
   0.00000000f, -0.09801714f, -0.19509032f, -0.29028468f,
  -0.38268343f, -0.47139674f, -0.55557023f, -0.63439328f,
  -0.70710678f, -0.77301045f, -0.83146961f, -0.88192126f,
  -0.92387953f, -0.95694034f, -0.98078528f, -0.99518473f,
  -1.00000000f, -0.99518473f, -0.98078528f, -0.95694034f,
  -0.92387953f, -0.88192126f, -0.83146961f, -0.77301045f,
  -0.70710678f, -0.63439328f, -0.55557023f, -0.47139674f,
  -0.38268343f, -0.29028468f, -0.19509032f, -0.09801714f,
   0.00000000f,  0.09801714f,  0.19509032f,  0.29028468f,
   0.38268343f,  0.47139674f,  0.55557023f,  0.63439328f,
   0.70710678f,  0.77301045f,  0.83146961f,  0.88192126f,
   0.92387953f,  0.95694034f,  0.98078528f,  0.99518473f,
};

#define NROWS 524288   // 16384 units * 32 a-rows

// ------- K0: sort modes by k (tie: original l); bit24 = run-end; invperm ----
__global__ __launch_bounds__(256) void k_sort(const int* __restrict__ mask,
                                              int* __restrict__ sorted,
                                              int* __restrict__ invperm) {
  __shared__ int ks[256];
  __shared__ int sv[256];
  __shared__ int skey[256];
  int t = threadIdx.x;
  int mi = mask[t];
  int j = mi / F1;
  int k = mi - j * F1;
  ks[t] = k;
  __syncthreads();
  int mykey = (k << 8) | t;
  int rank = 0;
  for (int l2 = 0; l2 < 256; ++l2)
    rank += (((ks[l2] << 8) | l2) < mykey);
  sv[rank]   = (k << 16) | (j << 8) | t;
  skey[rank] = k;
  invperm[t] = rank;                 // original index t -> sorted position
  __syncthreads();
  int isend = (t == 255) || (skey[t] != skey[t + 1]);
  sorted[t] = sv[t] | (isend << 24);
}

// ---------------- K1 v3: forward, 2-level DIF stage A (R9 version) ----------
__global__ __launch_bounds__(256, 4) void k_fwd(const float* __restrict__ x,
                                                const int* __restrict__ sorted,
                                                float2* __restrict__ xm) {
  __shared__ float2 rbuf[128][35];   // [row][k], pad 35
  __shared__ float2 cs32[32];        // (cos,sin)(2*pi*m/32)
  int t = threadIdx.x;
  if (t < 32) cs32[t] = make_float2(TWD[(2 * t) & 63], TWD[(2 * t + 48) & 63]);

  int rl  = t >> 1;
  int par = t & 1;
  size_t row = (size_t)blockIdx.x * 128 + rl;
  const float4* xp = (const float4*)(x + row * 64);

  float f[32];
#pragma unroll
  for (int q = 0; q < 16; ++q) {
    float4 v = xp[q];
    f[2 * q + 0] = par ? v.y : v.x;
    f[2 * q + 1] = par ? v.w : v.z;
  }

  float s1v[16], d1v[16];
#pragma unroll
  for (int m = 0; m < 16; ++m) {
    s1v[m] = f[m] + f[m + 16];
    d1v[m] = f[m] - f[m + 16];
  }
  float s2v[8], d2v[8];
#pragma unroll
  for (int m = 0; m < 8; ++m) {
    s2v[m] = s1v[m] + s1v[m + 8];
    d2v[m] = s1v[m] - s1v[m + 8];
  }
  float mR[17], mI[17];
#pragma unroll
  for (int j = 0; j < 17; ++j) { mR[j] = 0.f; mI[j] = 0.f; }
#pragma unroll
  for (int m = 0; m < 8; ++m) {
#pragma unroll
    for (int tq = 0; tq < 5; ++tq) {
      const int j = 4 * tq;
      const int a = (2 * j * m) & 63;        // compile-time
      const float c  = TWD[a];
      const float sn = TWD[(a + 48) & 63];
      if (c  != 0.0f) mR[j] = fmaf(s2v[m],  c,  mR[j]);
      if (sn != 0.0f) mI[j] = fmaf(s2v[m], -sn, mI[j]);
    }
  }
#pragma unroll
  for (int m = 0; m < 8; ++m) {
#pragma unroll
    for (int tq = 0; tq < 4; ++tq) {
      const int j = 4 * tq + 2;
      const int a = (2 * j * m) & 63;
      const float c  = TWD[a];
      const float sn = TWD[(a + 48) & 63];
      if (c  != 0.0f) mR[j] = fmaf(d2v[m],  c,  mR[j]);
      if (sn != 0.0f) mI[j] = fmaf(d2v[m], -sn, mI[j]);
    }
  }
#pragma unroll
  for (int m = 0; m < 16; ++m) {
#pragma unroll
    for (int r = 0; r < 8; ++r) {
      const int j = 2 * r + 1;
      const int a = (2 * j * m) & 63;
      const float c  = TWD[a];
      const float sn = TWD[(a + 48) & 63];
      if (c  != 0.0f) mR[j] = fmaf(d1v[m],  c,  mR[j]);
      if (sn != 0.0f) mI[j] = fmaf(d1v[m], -sn, mI[j]);
    }
  }

  float oR[17], oI[17];
#pragma unroll
  for (int j = 0; j < 17; ++j) {
    oR[j] = __shfl_xor(mR[j], 1, 64);
    oI[j] = __shfl_xor(mI[j], 1, 64);
  }

  if (par == 0) {
#pragma unroll
    for (int k = 0; k <= 16; ++k) {
      const float wr = TWD[k];
      const float s  = TWD[(k + 48) & 63];
      float XR = mR[k];
      float XI = mI[k];
      if (s  != 0.0f) { XR = fmaf( s, oI[k], XR); XI = fmaf(-s, oR[k], XI); }
      if (wr != 0.0f) { XR = fmaf(wr, oR[k], XR); XI = fmaf(wr, oI[k], XI); }
      rbuf[rl][k] = make_float2(XR, XI);
    }
  } else {
#pragma unroll
    for (int k = 17; k <= 31; ++k) {
      const float wr = TWD[k];
      const float s  = TWD[(k + 48) & 63];
      const int p = 32 - k;
      float XR = oR[p];
      float XI = -oI[p];
      if (s  != 0.0f) { XR = fmaf(-s, mI[p], XR); XI = fmaf(-s, mR[p], XI); }
      if (wr != 0.0f) { XR = fmaf(wr, mR[p], XR); XI = fmaf(-wr, mI[p], XI); }
      rbuf[rl][k] = make_float2(XR, XI);
    }
    rbuf[rl][32] = make_float2(oR[0] - mR[0], 0.0f);
  }
  __syncthreads();

  int e = sorted[t];
  int k = (e >> 16) & 63, j = (e >> 8) & 255, l = e & 255;
  float2 acc[4];
#pragma unroll
  for (int u = 0; u < 4; ++u) acc[u] = make_float2(0.f, 0.f);

#pragma unroll 4
  for (int s0 = 0; s0 < 32; ++s0) {
    float2 cs = cs32[(j * s0) & 31];
#pragma unroll
    for (int u = 0; u < 4; ++u) {
      float2 rv = rbuf[u * 32 + s0][k];
      acc[u].x = fmaf(rv.x, cs.x, fmaf(rv.y,  cs.y, acc[u].x));
      acc[u].y = fmaf(rv.y, cs.x, fmaf(-rv.x, cs.y, acc[u].y));
    }
  }
  size_t ub = (size_t)blockIdx.x * 4;
#pragma unroll
  for (int u = 0; u < 4; ++u)
    xm[(ub + u) * 256 + l] = acc[u];
}

// ---------------- K2 v7: v5 geometry + ic-split x2 (partial-om) --------------
// Grid 512 = ich(2) x h(8) x lgroup(32). Block ich accumulates ic in
// [4*ich, 4*ich+4) and writes its PARTIAL om to om0/om1. xm and W are
// partitioned by i -> zero fetch duplication, l-tile stays 8 (32B granule).
__global__ __launch_bounds__(512, 2) void k_mix(const float2* __restrict__ xm,
                                                const float* __restrict__ wr,
                                                const float* __restrict__ wi,
                                                float2* __restrict__ om0,
                                                float2* __restrict__ om1) {
  __shared__ float4 Asm4[8][4][33];  // 16.9 KB
  __shared__ float4 Wsm4[8][65][4];  // 33.3 KB
  int t = threadIdx.x;
  int ich = blockIdx.x >> 8;         // 0/1: ic half
  int bh8 = blockIdx.x & 255;
  int h  = bh8 >> 5;
  int lb = (bh8 & 31) * 8;

  int w    = t >> 6;        // wave id (0..7) -> o block
  int lane = t & 63;
  int b_lo = lane >> 2;     // 16 values
  int o_lo = lane & 3;      // 4 values

  float4 acc[2][2][4];
#pragma unroll
  for (int brp = 0; brp < 2; ++brp)
#pragma unroll
    for (int orp = 0; orp < 2; ++orp)
#pragma unroll
      for (int p = 0; p < 4; ++p)
        acc[brp][orp][p] = make_float4(0.f, 0.f, 0.f, 0.f);

  for (int ic = ich * 4; ic < ich * 4 + 4; ++ic) {
    __syncthreads();
#pragma unroll
    for (int q = 0; q < 2; ++q) {
      int c = t + 512 * q;
      int p = c & 3, ii = (c >> 2) & 7, b = c >> 5;
      const float4* src = (const float4*)(xm +
          (size_t)(((b * 8 + h) * 64) + ic * 8 + ii) * 256 + lb + 2 * p);
      Asm4[ii][p][b] = *src;
    }
#pragma unroll
    for (int q = 0; q < 2; ++q) {
      int c = t + 512 * q;
      int p2 = c & 1, oo = (c >> 1) & 63, ii = c >> 7;
      size_t gidx = (size_t)((h * 64 + ic * 8 + ii) * 64 + oo) * 256 + lb + p2 * 4;
      float4 vr = *(const float4*)(wr + gidx);
      float4 vi = *(const float4*)(wi + gidx);
      Wsm4[ii][oo][2 * p2 + 0] = make_float4(vr.x, vi.x, vr.y, vi.y);
      Wsm4[ii][oo][2 * p2 + 1] = make_float4(vr.z, vi.z, vr.w, vi.w);
    }
    __syncthreads();
#pragma unroll
    for (int i = 0; i < 8; ++i) {
      float4 av[2][4], wv[2][4];
#pragma unroll
      for (int brp = 0; brp < 2; ++brp)
#pragma unroll
        for (int p = 0; p < 4; ++p)
          av[brp][p] = Asm4[i][p][brp * 16 + b_lo];
#pragma unroll
      for (int orp = 0; orp < 2; ++orp)
#pragma unroll
        for (int p = 0; p < 4; ++p)
          wv[orp][p] = Wsm4[i][w * 8 + orp * 4 + o_lo][p];
#pragma unroll
      for (int brp = 0; brp < 2; ++brp)
#pragma unroll
        for (int orp = 0; orp < 2; ++orp)
#pragma unroll
          for (int p = 0; p < 4; ++p) {
            float4 A = av[brp][p], W = wv[orp][p];
            float4& C = acc[brp][orp][p];
            C.x = fmaf(A.x, W.x, fmaf(-A.y, W.y, C.x));
            C.y = fmaf(A.x, W.y, fmaf( A.y, W.x, C.y));
            C.z = fmaf(A.z, W.z, fmaf(-A.w, W.w, C.z));
            C.w = fmaf(A.z, W.w, fmaf( A.w, W.z, C.w));
          }
    }
  }
  float2* __restrict__ omo = ich ? om1 : om0;
#pragma unroll
  for (int brp = 0; brp < 2; ++brp)
#pragma unroll
    for (int orp = 0; orp < 2; ++orp)
#pragma unroll
      for (int p = 0; p < 4; ++p) {
        int b = brp * 16 + b_lo;
        int o = w * 8 + orp * 4 + o_lo;
        *(float4*)(omo + (size_t)(((b * 8 + h) * 64) + o) * 256 + lb + 2 * p)
            = acc[brp][orp][p];
      }
}

// ---------------- K3a: mode sum -> T[k][unit*32+a] (coalesced planes) -------
// Stages om = om0 + om1 (partial sums from the ic-split k_mix).
__global__ __launch_bounds__(256, 4) void k_inv_a(const float2* __restrict__ om0,
                                                  const float2* __restrict__ om1,
                                                  const int* __restrict__ sorted,
                                                  const int* __restrict__ invperm,
                                                  float* __restrict__ T) {
  __shared__ float4 om16s[16 * 128];  // 32.8 KB, sorted-order pairs
  __shared__ float2 cs32[32];
  __shared__ int4   smodes4[64];
  int t = threadIdx.x;
  size_t ub = (size_t)blockIdx.x * 16;

  {
    int pos = invperm[t];
    float2* dst = (float2*)om16s;
    const float2* omg0 = om0 + ub * 256;
    const float2* omg1 = om1 + ub * 256;
#pragma unroll
    for (int u = 0; u < 16; ++u) {
      float2 v0 = omg0[u * 256 + t];
      float2 v1 = omg1[u * 256 + t];
      dst[u * 256 + pos] = make_float2(v0.x + v1.x, v0.y + v1.y);
    }
  }
  if (t < 32) cs32[t] = make_float2(TWD[(2 * t) & 63], TWD[(2 * t + 48) & 63]);
  if (t < 64) smodes4[t] = ((const int4*)sorted)[t];
  __syncthreads();

  int up = t >> 5;          // unit-pair 0..7
  int a  = t & 31;
  int u0 = up * 2, u1 = u0 + 1;
  float g0 = 0.f, g1 = 0.f;
  long long seen = 0;       // 64-bit: shift by k (0..32) well-defined

#define PROC2(EV, R0, I0, R1, I1)                                             \
  do {                                                                        \
    int e_ = (EV);                                                            \
    int j_ = (e_ >> 8) & 255;                                                 \
    float2 cs_ = cs32[(j_ * a) & 31];                                         \
    g0 = fmaf((R0), cs_.x, g0); g0 = fmaf(-(I0), cs_.y, g0);                  \
    g1 = fmaf((R1), cs_.x, g1); g1 = fmaf(-(I1), cs_.y, g1);                  \
    if (e_ & (1 << 24)) {                                                     \
      int k_ = (e_ >> 16) & 63;                                               \
      seen |= 1ll << k_;                                                      \
      T[(size_t)k_ * NROWS + (ub + u0) * 32 + a] = g0;                        \
      T[(size_t)k_ * NROWS + (ub + u1) * 32 + a] = g1;                        \
      g0 = 0.f; g1 = 0.f;                                                     \
    }                                                                         \
  } while (0)

#pragma unroll 2
  for (int q = 0; q < 64; ++q) {
    int4   ee  = smodes4[q];
    float4 oA0 = om16s[u0 * 128 + 2 * q + 0];
    float4 oB0 = om16s[u0 * 128 + 2 * q + 1];
    float4 oA1 = om16s[u1 * 128 + 2 * q + 0];
    float4 oB1 = om16s[u1 * 128 + 2 * q + 1];
    PROC2(ee.x, oA0.x, oA0.y, oA1.x, oA1.y);
    PROC2(ee.y, oA0.z, oA0.w, oA1.z, oA1.w);
    PROC2(ee.z, oB0.x, oB0.y, oB1.x, oB1.y);
    PROC2(ee.w, oB0.z, oB0.w, oB1.z, oB1.w);
  }
#undef PROC2

#pragma unroll
  for (int k = 0; k < 33; ++k)
    if (!((seen >> k) & 1)) {
      T[(size_t)k * NROWS + (ub + u0) * 32 + a] = 0.f;
      T[(size_t)k * NROWS + (ub + u1) * 32 + a] = 0.f;
    }
}

// ---------------- K3b: exact compile-time cosine constants -------------------
template <int SG>
__device__ __forceinline__ void inv_b_body(const float (*T8)[34], int r,
                                           float* __restrict__ y, size_t Rb) {
  float acc[16];
  {
    float t0 = T8[r][0];
#pragma unroll
    for (int o = 0; o < 16; ++o)
      acc[o] = t0 * (1.0f / 2048.0f);          // k=0: cos=1
  }
#pragma unroll
  for (int k = 1; k < 33; ++k) {
    float tk = T8[r][k];
#pragma unroll
    for (int o = 0; o < 16; ++o) {
      const float C = ((k == 32) ? (1.0f / 2048.0f) : (2.0f / 2048.0f))
                    * TWD[(k * (SG * 16 + o)) & 63];   // compile-time literal
      if (C != 0.0f) acc[o] = fmaf(tk, C, acc[o]);
    }
  }
  float* yp = y + (Rb + r) * 64 + SG * 16;
#pragma unroll
  for (int q = 0; q < 4; ++q)
    *(float4*)(yp + 4 * q) = make_float4(acc[4 * q + 0], acc[4 * q + 1],
                                         acc[4 * q + 2], acc[4 * q + 3]);
}

__global__ __launch_bounds__(256, 4) void k_inv_b(const float* __restrict__ T,
                                                  float* __restrict__ y) {
  __shared__ float T8[64][34];
  int t = threadIdx.x;
  size_t Rb = (size_t)blockIdx.x * 64;

#pragma unroll
  for (int q = 0; q < 9; ++q) {
    int c = t + 256 * q;
    if (c < 2112) {
      int kq = c >> 6, r = c & 63;
      T8[r][kq] = T[(size_t)kq * NROWS + Rb + r];   // coalesced 256B runs
    }
  }
  __syncthreads();

  int wv = t >> 6;          // wave-uniform sg
  int r  = t & 63;
  if      (wv == 0) inv_b_body<0>(T8, r, y, Rb);
  else if (wv == 1) inv_b_body<1>(T8, r, y, Rb);
  else if (wv == 2) inv_b_body<2>(T8, r, y, Rb);
  else              inv_b_body<3>(T8, r, y, Rb);
}

// ---------------- K3 v7 fallback (if ws too small): R9 version --------------
__global__ __launch_bounds__(512, 4) void k_inv(const float2* __restrict__ om0,
                                                const float2* __restrict__ om1,
                                                const int* __restrict__ sorted,
                                                const int* __restrict__ invperm,
                                                float* __restrict__ y) {
  __shared__ float4 om8s[8 * 128];
  __shared__ float  c2s[33][64];
  __shared__ float2 cs32[32];
  __shared__ int4   smodes4[64];
  int t = threadIdx.x;
  size_t ub = (size_t)blockIdx.x * 8;

  {
    int l  = t & 255;
    int u0 = t >> 8;
    int pos = invperm[l];
    float2* dst = (float2*)om8s;
    const float2* omg0 = om0 + ub * 256;
    const float2* omg1 = om1 + ub * 256;
#pragma unroll
    for (int q = 0; q < 4; ++q) {
      int u = u0 + 2 * q;
      float2 v0 = omg0[u * 256 + l];
      float2 v1 = omg1[u * 256 + l];
      dst[u * 256 + pos] = make_float2(v0.x + v1.x, v0.y + v1.y);
    }
  }
#pragma unroll
  for (int q = 0; q < 5; ++q) {
    int idx = t + 512 * q;
    if (idx < 2112) {
      int k = idx >> 6, s1 = idx & 63;
      float w = (k == 0 || k == 32) ? (1.0f / 2048.0f) : (2.0f / 2048.0f);
      c2s[k][s1] = w * TWD[(k * s1) & 63];
    }
  }
  if (t < 32) cs32[t] = make_float2(TWD[(2 * t) & 63], TWD[(2 * t + 48) & 63]);
  if (t < 64) smodes4[t] = ((const int4*)sorted)[t];
  __syncthreads();

  int u    = t >> 6;
  int a    = (t >> 1) & 31;
  int half = t & 1;

  float4 a0 = make_float4(0.f,0.f,0.f,0.f), a1 = a0, a2 = a0, a3 = a0;
  float4 a4 = a0, a5 = a0, a6 = a0, a7 = a0;
  float g = 0.f;

#define SPREAD(KK)                                                            \
  do {                                                                        \
    const float4* crow = (const float4*)&c2s[(KK)][half * 32];                \
    float4 c;                                                                 \
    c = crow[0]; a0.x=fmaf(g,c.x,a0.x); a0.y=fmaf(g,c.y,a0.y); a0.z=fmaf(g,c.z,a0.z); a0.w=fmaf(g,c.w,a0.w); \
    c = crow[1]; a1.x=fmaf(g,c.x,a1.x); a1.y=fmaf(g,c.y,a1.y); a1.z=fmaf(g,c.z,a1.z); a1.w=fmaf(g,c.w,a1.w); \
    c = crow[2]; a2.x=fmaf(g,c.x,a2.x); a2.y=fmaf(g,c.y,a2.y); a2.z=fmaf(g,c.z,a2.z); a2.w=fmaf(g,c.w,a2.w); \
    c = crow[3]; a3.x=fmaf(g,c.x,a3.x); a3.y=fmaf(g,c.y,a3.y); a3.z=fmaf(g,c.z,a3.z); a3.w=fmaf(g,c.w,a3.w); \
    c = crow[4]; a4.x=fmaf(g,c.x,a4.x); a4.y=fmaf(g,c.y,a4.y); a4.z=fmaf(g,c.z,a4.z); a4.w=fmaf(g,c.w,a4.w); \
    c = crow[5]; a5.x=fmaf(g,c.x,a5.x); a5.y=fmaf(g,c.y,a5.y); a5.z=fmaf(g,c.z,a5.z); a5.w=fmaf(g,c.w,a5.w); \
    c = crow[6]; a6.x=fmaf(g,c.x,a6.x); a6.y=fmaf(g,c.y,a6.y); a6.z=fmaf(g,c.z,a6.z); a6.w=fmaf(g,c.w,a6.w); \
    c = crow[7]; a7.x=fmaf(g,c.x,a7.x); a7.y=fmaf(g,c.y,a7.y); a7.z=fmaf(g,c.z,a7.z); a7.w=fmaf(g,c.w,a7.w); \
    g = 0.f;                                                                  \
  } while (0)

#define PROC(EV, OVR, OVI)                                                    \
  do {                                                                        \
    int e_ = (EV);                                                            \
    int j_ = (e_ >> 8) & 255;                                                 \
    float2 cs_ = cs32[(j_ * a) & 31];                                         \
    g = fmaf((OVR), cs_.x, g);                                                \
    g = fmaf(-(OVI), cs_.y, g);                                               \
    if (e_ & (1 << 24)) SPREAD((e_ >> 16) & 63);                              \
  } while (0)

#pragma unroll 2
  for (int q = 0; q < 64; ++q) {
    int4   ee = smodes4[q];
    float4 oA = om8s[u * 128 + 2 * q + 0];
    float4 oB = om8s[u * 128 + 2 * q + 1];
    PROC(ee.x, oA.x, oA.y);
    PROC(ee.y, oA.z, oA.w);
    PROC(ee.z, oB.x, oB.y);
    PROC(ee.w, oB.z, oB.w);
  }
#undef PROC
#undef SPREAD

  float4* yp = (float4*)(y + (ub + u) * 2048 + a * 64 + half * 32);
  yp[0] = a0; yp[1] = a1; yp[2] = a2; yp[3] = a3;
  yp[4] = a4; yp[5] = a5; yp[6] = a6; yp[7] = a7;
}

extern "C" void kernel_launch(void* const* d_in, const int* in_sizes, int n_in,
                              void* d_out, int out_size, void* d_ws, size_t ws_size,
                              hipStream_t stream) {
  const float* x    = (const float*)d_in[0];
  const float* wre  = (const float*)d_in[1];
  const float* wim  = (const float*)d_in[2];
  const int*   mask = (const int*)d_in[3];

  float*  y  = (float*)d_out;
  float2* xm = (float2*)d_out;                        // [0, 33.55 MB): dead before y
  float2* om1 = (float2*)d_out + 4194304;             // [33.55, 67.1 MB) of d_out:
                                                      //   dead until k_inv_b writes y
  char* base = (char*)d_ws;
  float2* om0   = (float2*)d_ws;                      // 33.55 MB
  int*  sorted  = (int*)(base + 33554432);            // 1 KB (16B-aligned)
  int*  invperm = (int*)(base + 33555456);            // 1 KB
  float* T      = (float*)(base + 33556480);          // 69.2 MB (if available)
  const size_t ws_needed = 33556480ull + (size_t)33 * NROWS * 4;

  k_sort<<<1, 256, 0, stream>>>(mask, sorted, invperm);
  k_fwd <<<4096, 256, 0, stream>>>(x, sorted, xm);
  k_mix <<<512, 512, 0, stream>>>(xm, wre, wim, om0, om1);
  if (ws_size >= ws_needed) {
    k_inv_a<<<1024, 256, 0, stream>>>(om0, om1, sorted, invperm, T);
    k_inv_b<<<8192, 256, 0, stream>>>(T, y);
  } else {
    k_inv<<<2048, 512, 0, stream>>>(om0, om1, sorted, invperm, y);
  }
}

// Round 19
// 209.885 us; speedup vs baseline: 1.2789x; 1.1356x over previous
//
#include <hip/hip_runtime.h>

#define F1 33

// cos(2*pi*m/64); sin(2*pi*m/64) = TWD[(m+48)&63]
constexpr float TWD[64] = {
   1.00000000f,  0.99518473f,  0.98078528f,  0.95694034f,
   0.92387953f,  0.88192126f,  0.83146961f,  0.77301045f,
   0.70710678f,  0.63439328f,  0.55557023f,  0.47139674f,
   0.38268343f,  0.29028468f,  0.19509032f,  0.09801714f,
   0.00000000f, -0.09801714f, -0.19509032f, -0.29028468f,
  -0.38268343f, -0.47139674f, -0.55557023f, -0.63439328f,
  -0.70710678f, -0.77301045f, -0.83146961f, -0.88192126f,
  -0.92387953f, -0.95694034f, -0.98078528f, -0.99518473f,
  -1.00000000f, -0.99518473f, -0.98078528f, -0.95694034f,
  -0.92387953f, -0.88192126f, -0.83146961f, -0.77301045f,
  -0.70710678f, -0.63439328f, -0.55557023f, -0.47139674f,
  -0.38268343f, -0.29028468f, -0.19509032f, -0.09801714f,
   0.00000000f,  0.09801714f,  0.19509032f,  0.29028468f,
   0.38268343f,  0.47139674f,  0.55557023f,  0.63439328f,
   0.70710678f,  0.77301045f,  0.83146961f,  0.88192126f,
   0.92387953f,  0.95694034f,  0.98078528f,  0.99518473f,
};

#define NROWS 524288   // 16384 units * 32 a-rows

// ------- K0: sort modes by k (tie: original l); bit24 = run-end; invperm ----
__global__ __launch_bounds__(256) void k_sort(const int* __restrict__ mask,
                                              int* __restrict__ sorted,
                                              int* __restrict__ invperm) {
  __shared__ int ks[256];
  __shared__ int sv[256];
  __shared__ int skey[256];
  int t = threadIdx.x;
  int mi = mask[t];
  int j = mi / F1;
  int k = mi - j * F1;
  ks[t] = k;
  __syncthreads();
  int mykey = (k << 8) | t;
  int rank = 0;
  for (int l2 = 0; l2 < 256; ++l2)
    rank += (((ks[l2] << 8) | l2) < mykey);
  sv[rank]   = (k << 16) | (j << 8) | t;
  skey[rank] = k;
  invperm[t] = rank;                 // original index t -> sorted position
  __syncthreads();
  int isend = (t == 255) || (skey[t] != skey[t + 1]);
  sorted[t] = sv[t] | (isend << 24);
}

// ---------------- K1 v3: forward, 2-level DIF stage A (R9 version) ----------
__global__ __launch_bounds__(256, 4) void k_fwd(const float* __restrict__ x,
                                                const int* __restrict__ sorted,
                                                float2* __restrict__ xm) {
  __shared__ float2 rbuf[128][35];   // [row][k], pad 35
  __shared__ float2 cs32[32];        // (cos,sin)(2*pi*m/32)
  int t = threadIdx.x;
  if (t < 32) cs32[t] = make_float2(TWD[(2 * t) & 63], TWD[(2 * t + 48) & 63]);

  int rl  = t >> 1;
  int par = t & 1;
  size_t row = (size_t)blockIdx.x * 128 + rl;
  const float4* xp = (const float4*)(x + row * 64);

  float f[32];
#pragma unroll
  for (int q = 0; q < 16; ++q) {
    float4 v = xp[q];
    f[2 * q + 0] = par ? v.y : v.x;
    f[2 * q + 1] = par ? v.w : v.z;
  }

  float s1v[16], d1v[16];
#pragma unroll
  for (int m = 0; m < 16; ++m) {
    s1v[m] = f[m] + f[m + 16];
    d1v[m] = f[m] - f[m + 16];
  }
  float s2v[8], d2v[8];
#pragma unroll
  for (int m = 0; m < 8; ++m) {
    s2v[m] = s1v[m] + s1v[m + 8];
    d2v[m] = s1v[m] - s1v[m + 8];
  }
  float mR[17], mI[17];
#pragma unroll
  for (int j = 0; j < 17; ++j) { mR[j] = 0.f; mI[j] = 0.f; }
#pragma unroll
  for (int m = 0; m < 8; ++m) {
#pragma unroll
    for (int tq = 0; tq < 5; ++tq) {
      const int j = 4 * tq;
      const int a = (2 * j * m) & 63;        // compile-time
      const float c  = TWD[a];
      const float sn = TWD[(a + 48) & 63];
      if (c  != 0.0f) mR[j] = fmaf(s2v[m],  c,  mR[j]);
      if (sn != 0.0f) mI[j] = fmaf(s2v[m], -sn, mI[j]);
    }
  }
#pragma unroll
  for (int m = 0; m < 8; ++m) {
#pragma unroll
    for (int tq = 0; tq < 4; ++tq) {
      const int j = 4 * tq + 2;
      const int a = (2 * j * m) & 63;
      const float c  = TWD[a];
      const float sn = TWD[(a + 48) & 63];
      if (c  != 0.0f) mR[j] = fmaf(d2v[m],  c,  mR[j]);
      if (sn != 0.0f) mI[j] = fmaf(d2v[m], -sn, mI[j]);
    }
  }
#pragma unroll
  for (int m = 0; m < 16; ++m) {
#pragma unroll
    for (int r = 0; r < 8; ++r) {
      const int j = 2 * r + 1;
      const int a = (2 * j * m) & 63;
      const float c  = TWD[a];
      const float sn = TWD[(a + 48) & 63];
      if (c  != 0.0f) mR[j] = fmaf(d1v[m],  c,  mR[j]);
      if (sn != 0.0f) mI[j] = fmaf(d1v[m], -sn, mI[j]);
    }
  }

  float oR[17], oI[17];
#pragma unroll
  for (int j = 0; j < 17; ++j) {
    oR[j] = __shfl_xor(mR[j], 1, 64);
    oI[j] = __shfl_xor(mI[j], 1, 64);
  }

  if (par == 0) {
#pragma unroll
    for (int k = 0; k <= 16; ++k) {
      const float wr = TWD[k];
      const float s  = TWD[(k + 48) & 63];
      float XR = mR[k];
      float XI = mI[k];
      if (s  != 0.0f) { XR = fmaf( s, oI[k], XR); XI = fmaf(-s, oR[k], XI); }
      if (wr != 0.0f) { XR = fmaf(wr, oR[k], XR); XI = fmaf(wr, oI[k], XI); }
      rbuf[rl][k] = make_float2(XR, XI);
    }
  } else {
#pragma unroll
    for (int k = 17; k <= 31; ++k) {
      const float wr = TWD[k];
      const float s  = TWD[(k + 48) & 63];
      const int p = 32 - k;
      float XR = oR[p];
      float XI = -oI[p];
      if (s  != 0.0f) { XR = fmaf(-s, mI[p], XR); XI = fmaf(-s, mR[p], XI); }
      if (wr != 0.0f) { XR = fmaf(wr, mR[p], XR); XI = fmaf(-wr, mI[p], XI); }
      rbuf[rl][k] = make_float2(XR, XI);
    }
    rbuf[rl][32] = make_float2(oR[0] - mR[0], 0.0f);
  }
  __syncthreads();

  int e = sorted[t];
  int k = (e >> 16) & 63, j = (e >> 8) & 255, l = e & 255;
  float2 acc[4];
#pragma unroll
  for (int u = 0; u < 4; ++u) acc[u] = make_float2(0.f, 0.f);

#pragma unroll 4
  for (int s0 = 0; s0 < 32; ++s0) {
    float2 cs = cs32[(j * s0) & 31];
#pragma unroll
    for (int u = 0; u < 4; ++u) {
      float2 rv = rbuf[u * 32 + s0][k];
      acc[u].x = fmaf(rv.x, cs.x, fmaf(rv.y,  cs.y, acc[u].x));
      acc[u].y = fmaf(rv.y, cs.x, fmaf(-rv.x, cs.y, acc[u].y));
    }
  }
  size_t ub = (size_t)blockIdx.x * 4;
#pragma unroll
  for (int u = 0; u < 4; ++u)
    xm[(ub + u) * 256 + l] = acc[u];
}

// ---------------- K2 v8: v5 geometry + XCD-chunked block swizzle -------------
// swz = (bid&7)*32 + bid>>3 (bijective, 256%8==0): all 32 lb-blocks of one h
// land on ONE XCD -> the 64B lines shared by adjacent lb-blocks (32B W/xm
// slices of the same 1KB rows) are fetched once per XCD, not twice.
__global__ __launch_bounds__(512, 2) void k_mix(const float2* __restrict__ xm,
                                                const float* __restrict__ wr,
                                                const float* __restrict__ wi,
                                                float2* __restrict__ om) {
  __shared__ float4 Asm4[8][4][33];  // 16.9 KB
  __shared__ float4 Wsm4[8][65][4];  // 33.3 KB
  int t = threadIdx.x;
  int swz = (blockIdx.x & 7) * 32 + (blockIdx.x >> 3);   // XCD-chunked
  int h  = swz >> 5;
  int lb = (swz & 31) * 8;

  int w    = t >> 6;        // wave id (0..7) -> o block
  int lane = t & 63;
  int b_lo = lane >> 2;     // 16 values
  int o_lo = lane & 3;      // 4 values

  float4 acc[2][2][4];
#pragma unroll
  for (int brp = 0; brp < 2; ++brp)
#pragma unroll
    for (int orp = 0; orp < 2; ++orp)
#pragma unroll
      for (int p = 0; p < 4; ++p)
        acc[brp][orp][p] = make_float4(0.f, 0.f, 0.f, 0.f);

  for (int ic = 0; ic < 8; ++ic) {
    __syncthreads();
#pragma unroll
    for (int q = 0; q < 2; ++q) {
      int c = t + 512 * q;
      int p = c & 3, ii = (c >> 2) & 7, b = c >> 5;
      const float4* src = (const float4*)(xm +
          (size_t)(((b * 8 + h) * 64) + ic * 8 + ii) * 256 + lb + 2 * p);
      Asm4[ii][p][b] = *src;
    }
#pragma unroll
    for (int q = 0; q < 2; ++q) {
      int c = t + 512 * q;
      int p2 = c & 1, oo = (c >> 1) & 63, ii = c >> 7;
      size_t gidx = (size_t)((h * 64 + ic * 8 + ii) * 64 + oo) * 256 + lb + p2 * 4;
      float4 vr = *(const float4*)(wr + gidx);
      float4 vi = *(const float4*)(wi + gidx);
      Wsm4[ii][oo][2 * p2 + 0] = make_float4(vr.x, vi.x, vr.y, vi.y);
      Wsm4[ii][oo][2 * p2 + 1] = make_float4(vr.z, vi.z, vr.w, vi.w);
    }
    __syncthreads();
#pragma unroll
    for (int i = 0; i < 8; ++i) {
      float4 av[2][4], wv[2][4];
#pragma unroll
      for (int brp = 0; brp < 2; ++brp)
#pragma unroll
        for (int p = 0; p < 4; ++p)
          av[brp][p] = Asm4[i][p][brp * 16 + b_lo];
#pragma unroll
      for (int orp = 0; orp < 2; ++orp)
#pragma unroll
        for (int p = 0; p < 4; ++p)
          wv[orp][p] = Wsm4[i][w * 8 + orp * 4 + o_lo][p];
#pragma unroll
      for (int brp = 0; brp < 2; ++brp)
#pragma unroll
        for (int orp = 0; orp < 2; ++orp)
#pragma unroll
          for (int p = 0; p < 4; ++p) {
            float4 A = av[brp][p], W = wv[orp][p];
            float4& C = acc[brp][orp][p];
            C.x = fmaf(A.x, W.x, fmaf(-A.y, W.y, C.x));
            C.y = fmaf(A.x, W.y, fmaf( A.y, W.x, C.y));
            C.z = fmaf(A.z, W.z, fmaf(-A.w, W.w, C.z));
            C.w = fmaf(A.z, W.w, fmaf( A.w, W.z, C.w));
          }
    }
  }
#pragma unroll
  for (int brp = 0; brp < 2; ++brp)
#pragma unroll
    for (int orp = 0; orp < 2; ++orp)
#pragma unroll
      for (int p = 0; p < 4; ++p) {
        int b = brp * 16 + b_lo;
        int o = w * 8 + orp * 4 + o_lo;
        *(float4*)(om + (size_t)(((b * 8 + h) * 64) + o) * 256 + lb + 2 * p)
            = acc[brp][orp][p];
      }
}

// ---------------- K3a: mode sum -> T[k][unit*32+a] (coalesced planes) -------
// Per-thread 64-bit `seen` bitmask marks flushed k planes; absent ones
// zero-filled by the SAME thread afterwards.
__global__ __launch_bounds__(256, 4) void k_inv_a(const float2* __restrict__ om,
                                                  const int* __restrict__ sorted,
                                                  const int* __restrict__ invperm,
                                                  float* __restrict__ T) {
  __shared__ float4 om16s[16 * 128];  // 32.8 KB, sorted-order pairs
  __shared__ float2 cs32[32];
  __shared__ int4   smodes4[64];
  int t = threadIdx.x;
  size_t ub = (size_t)blockIdx.x * 16;

  {
    int pos = invperm[t];
    float2* dst = (float2*)om16s;
    const float2* omg = om + ub * 256;
#pragma unroll
    for (int u = 0; u < 16; ++u)
      dst[u * 256 + pos] = omg[u * 256 + t];
  }
  if (t < 32) cs32[t] = make_float2(TWD[(2 * t) & 63], TWD[(2 * t + 48) & 63]);
  if (t < 64) smodes4[t] = ((const int4*)sorted)[t];
  __syncthreads();

  int up = t >> 5;          // unit-pair 0..7
  int a  = t & 31;
  int u0 = up * 2, u1 = u0 + 1;
  float g0 = 0.f, g1 = 0.f;
  long long seen = 0;       // 64-bit: shift by k (0..32) well-defined

#define PROC2(EV, R0, I0, R1, I1)                                             \
  do {                                                                        \
    int e_ = (EV);                                                            \
    int j_ = (e_ >> 8) & 255;                                                 \
    float2 cs_ = cs32[(j_ * a) & 31];                                         \
    g0 = fmaf((R0), cs_.x, g0); g0 = fmaf(-(I0), cs_.y, g0);                  \
    g1 = fmaf((R1), cs_.x, g1); g1 = fmaf(-(I1), cs_.y, g1);                  \
    if (e_ & (1 << 24)) {                                                     \
      int k_ = (e_ >> 16) & 63;                                               \
      seen |= 1ll << k_;                                                      \
      T[(size_t)k_ * NROWS + (ub + u0) * 32 + a] = g0;                        \
      T[(size_t)k_ * NROWS + (ub + u1) * 32 + a] = g1;                        \
      g0 = 0.f; g1 = 0.f;                                                     \
    }                                                                         \
  } while (0)

#pragma unroll 2
  for (int q = 0; q < 64; ++q) {
    int4   ee  = smodes4[q];
    float4 oA0 = om16s[u0 * 128 + 2 * q + 0];
    float4 oB0 = om16s[u0 * 128 + 2 * q + 1];
    float4 oA1 = om16s[u1 * 128 + 2 * q + 0];
    float4 oB1 = om16s[u1 * 128 + 2 * q + 1];
    PROC2(ee.x, oA0.x, oA0.y, oA1.x, oA1.y);
    PROC2(ee.y, oA0.z, oA0.w, oA1.z, oA1.w);
    PROC2(ee.z, oB0.x, oB0.y, oB1.x, oB1.y);
    PROC2(ee.w, oB0.z, oB0.w, oB1.z, oB1.w);
  }
#undef PROC2

#pragma unroll
  for (int k = 0; k < 33; ++k)
    if (!((seen >> k) & 1)) {
      T[(size_t)k * NROWS + (ub + u0) * 32 + a] = 0.f;
      T[(size_t)k * NROWS + (ub + u1) * 32 + a] = 0.f;
    }
}

// ---------------- K3b: exact compile-time cosine constants -------------------
template <int SG>
__device__ __forceinline__ void inv_b_body(const float (*T8)[34], int r,
                                           float* __restrict__ y, size_t Rb) {
  float acc[16];
  {
    float t0 = T8[r][0];
#pragma unroll
    for (int o = 0; o < 16; ++o)
      acc[o] = t0 * (1.0f / 2048.0f);          // k=0: cos=1
  }
#pragma unroll
  for (int k = 1; k < 33; ++k) {
    float tk = T8[r][k];
#pragma unroll
    for (int o = 0; o < 16; ++o) {
      const float C = ((k == 32) ? (1.0f / 2048.0f) : (2.0f / 2048.0f))
                    * TWD[(k * (SG * 16 + o)) & 63];   // compile-time literal
      if (C != 0.0f) acc[o] = fmaf(tk, C, acc[o]);
    }
  }
  float* yp = y + (Rb + r) * 64 + SG * 16;
#pragma unroll
  for (int q = 0; q < 4; ++q)
    *(float4*)(yp + 4 * q) = make_float4(acc[4 * q + 0], acc[4 * q + 1],
                                         acc[4 * q + 2], acc[4 * q + 3]);
}

__global__ __launch_bounds__(256, 4) void k_inv_b(const float* __restrict__ T,
                                                  float* __restrict__ y) {
  __shared__ float T8[64][34];
  int t = threadIdx.x;
  size_t Rb = (size_t)blockIdx.x * 64;

#pragma unroll
  for (int q = 0; q < 9; ++q) {
    int c = t + 256 * q;
    if (c < 2112) {
      int kq = c >> 6, r = c & 63;
      T8[r][kq] = T[(size_t)kq * NROWS + Rb + r];   // coalesced 256B runs
    }
  }
  __syncthreads();

  int wv = t >> 6;          // wave-uniform sg
  int r  = t & 63;
  if      (wv == 0) inv_b_body<0>(T8, r, y, Rb);
  else if (wv == 1) inv_b_body<1>(T8, r, y, Rb);
  else if (wv == 2) inv_b_body<2>(T8, r, y, Rb);
  else              inv_b_body<3>(T8, r, y, Rb);
}

// ---------------- K3 v7 fallback (if ws too small): R9 version --------------
__global__ __launch_bounds__(512, 4) void k_inv(const float2* __restrict__ om,
                                                const int* __restrict__ sorted,
                                                const int* __restrict__ invperm,
                                                float* __restrict__ y) {
  __shared__ float4 om8s[8 * 128];
  __shared__ float  c2s[33][64];
  __shared__ float2 cs32[32];
  __shared__ int4   smodes4[64];
  int t = threadIdx.x;
  size_t ub = (size_t)blockIdx.x * 8;

  {
    int l  = t & 255;
    int u0 = t >> 8;
    int pos = invperm[l];
    float2* dst = (float2*)om8s;
    const float2* omg = om + ub * 256;
#pragma unroll
    for (int q = 0; q < 4; ++q) {
      int u = u0 + 2 * q;
      dst[u * 256 + pos] = omg[u * 256 + l];
    }
  }
#pragma unroll
  for (int q = 0; q < 5; ++q) {
    int idx = t + 512 * q;
    if (idx < 2112) {
      int k = idx >> 6, s1 = idx & 63;
      float w = (k == 0 || k == 32) ? (1.0f / 2048.0f) : (2.0f / 2048.0f);
      c2s[k][s1] = w * TWD[(k * s1) & 63];
    }
  }
  if (t < 32) cs32[t] = make_float2(TWD[(2 * t) & 63], TWD[(2 * t + 48) & 63]);
  if (t < 64) smodes4[t] = ((const int4*)sorted)[t];
  __syncthreads();

  int u    = t >> 6;
  int a    = (t >> 1) & 31;
  int half = t & 1;

  float4 a0 = make_float4(0.f,0.f,0.f,0.f), a1 = a0, a2 = a0, a3 = a0;
  float4 a4 = a0, a5 = a0, a6 = a0, a7 = a0;
  float g = 0.f;

#define SPREAD(KK)                                                            \
  do {                                                                        \
    const float4* crow = (const float4*)&c2s[(KK)][half * 32];                \
    float4 c;                                                                 \
    c = crow[0]; a0.x=fmaf(g,c.x,a0.x); a0.y=fmaf(g,c.y,a0.y); a0.z=fmaf(g,c.z,a0.z); a0.w=fmaf(g,c.w,a0.w); \
    c = crow[1]; a1.x=fmaf(g,c.x,a1.x); a1.y=fmaf(g,c.y,a1.y); a1.z=fmaf(g,c.z,a1.z); a1.w=fmaf(g,c.w,a1.w); \
    c = crow[2]; a2.x=fmaf(g,c.x,a2.x); a2.y=fmaf(g,c.y,a2.y); a2.z=fmaf(g,c.z,a2.z); a2.w=fmaf(g,c.w,a2.w); \
    c = crow[3]; a3.x=fmaf(g,c.x,a3.x); a3.y=fmaf(g,c.y,a3.y); a3.z=fmaf(g,c.z,a3.z); a3.w=fmaf(g,c.w,a3.w); \
    c = crow[4]; a4.x=fmaf(g,c.x,a4.x); a4.y=fmaf(g,c.y,a4.y); a4.z=fmaf(g,c.z,a4.z); a4.w=fmaf(g,c.w,a4.w); \
    c = crow[5]; a5.x=fmaf(g,c.x,a5.x); a5.y=fmaf(g,c.y,a5.y); a5.z=fmaf(g,c.z,a5.z); a5.w=fmaf(g,c.w,a5.w); \
    c = crow[6]; a6.x=fmaf(g,c.x,a6.x); a6.y=fmaf(g,c.y,a6.y); a6.z=fmaf(g,c.z,a6.z); a6.w=fmaf(g,c.w,a6.w); \
    c = crow[7]; a7.x=fmaf(g,c.x,a7.x); a7.y=fmaf(g,c.y,a7.y); a7.z=fmaf(g,c.z,a7.z); a7.w=fmaf(g,c.w,a7.w); \
    g = 0.f;                                                                  \
  } while (0)

#define PROC(EV, OVR, OVI)                                                    \
  do {                                                                        \
    int e_ = (EV);                                                            \
    int j_ = (e_ >> 8) & 255;                                                 \
    float2 cs_ = cs32[(j_ * a) & 31];                                         \
    g = fmaf((OVR), cs_.x, g);                                                \
    g = fmaf(-(OVI), cs_.y, g);                                               \
    if (e_ & (1 << 24)) SPREAD((e_ >> 16) & 63);                              \
  } while (0)

#pragma unroll 2
  for (int q = 0; q < 64; ++q) {
    int4   ee = smodes4[q];
    float4 oA = om8s[u * 128 + 2 * q + 0];
    float4 oB = om8s[u * 128 + 2 * q + 1];
    PROC(ee.x, oA.x, oA.y);
    PROC(ee.y, oA.z, oA.w);
    PROC(ee.z, oB.x, oB.y);
    PROC(ee.w, oB.z, oB.w);
  }
#undef PROC
#undef SPREAD

  float4* yp = (float4*)(y + (ub + u) * 2048 + a * 64 + half * 32);
  yp[0] = a0; yp[1] = a1; yp[2] = a2; yp[3] = a3;
  yp[4] = a4; yp[5] = a5; yp[6] = a6; yp[7] = a7;
}

extern "C" void kernel_launch(void* const* d_in, const int* in_sizes, int n_in,
                              void* d_out, int out_size, void* d_ws, size_t ws_size,
                              hipStream_t stream) {
  const float* x    = (const float*)d_in[0];
  const float* wre  = (const float*)d_in[1];
  const float* wim  = (const float*)d_in[2];
  const int*   mask = (const int*)d_in[3];

  float*  y  = (float*)d_out;
  float2* xm = (float2*)d_out;                        // scratch: dead before y written
  char* base = (char*)d_ws;
  float2* omp   = (float2*)d_ws;                      // 33.55 MB
  int*  sorted  = (int*)(base + 33554432);            // 1 KB (16B-aligned)
  int*  invperm = (int*)(base + 33555456);            // 1 KB
  float* T      = (float*)(base + 33556480);          // 69.2 MB (if available)
  const size_t ws_needed = 33556480ull + (size_t)33 * NROWS * 4;

  k_sort<<<1, 256, 0, stream>>>(mask, sorted, invperm);
  k_fwd <<<4096, 256, 0, stream>>>(x, sorted, xm);
  k_mix <<<256, 512, 0, stream>>>(xm, wre, wim, omp);
  if (ws_size >= ws_needed) {
    k_inv_a<<<1024, 256, 0, stream>>>(omp, sorted, invperm, T);
    k_inv_b<<<8192, 256, 0, stream>>>(T, y);
  } else {
    k_inv<<<2048, 512, 0, stream>>>(omp, sorted, invperm, y);
  }
}

// Round 20
// 205.951 us; speedup vs baseline: 1.3033x; 1.0191x over previous
//
#include <hip/hip_runtime.h>

#define F1 33

// cos(2*pi*m/64); sin(2*pi*m/64) = TWD[(m+48)&63]
constexpr float TWD[64] = {
   1.00000000f,  0.99518473f,  0.98078528f,  0.95694034f,
   0.92387953f,  0.88192126f,  0.83146961f,  0.77301045f,
   0.70710678f,  0.63439328f,  0.55557023f,  0.47139674f,
   0.38268343f,  0.29028468f,  0.19509032f,  0.09801714f,
   0.00000000f, -0.09801714f, -0.19509032f, -0.29028468f,
  -0.38268343f, -0.47139674f, -0.55557023f, -0.63439328f,
  -0.70710678f, -0.77301045f, -0.83146961f, -0.88192126f,
  -0.92387953f, -0.95694034f, -0.98078528f, -0.99518473f,
  -1.00000000f, -0.99518473f, -0.98078528f, -0.95694034f,
  -0.92387953f, -0.88192126f, -0.83146961f, -0.77301045f,
  -0.70710678f, -0.63439328f, -0.55557023f, -0.47139674f,
  -0.38268343f, -0.29028468f, -0.19509032f, -0.09801714f,
   0.00000000f,  0.09801714f,  0.19509032f,  0.29028468f,
   0.38268343f,  0.47139674f,  0.55557023f,  0.63439328f,
   0.70710678f,  0.77301045f,  0.83146961f,  0.88192126f,
   0.92387953f,  0.95694034f,  0.98078528f,  0.99518473f,
};

#define NROWS 524288   // 16384 units * 32 a-rows

// ------- K0: sort modes by k (tie: original l); bit24 = run-end; invperm ----
__global__ __launch_bounds__(256) void k_sort(const int* __restrict__ mask,
                                              int* __restrict__ sorted,
                                              int* __restrict__ invperm) {
  __shared__ int ks[256];
  __shared__ int sv[256];
  __shared__ int skey[256];
  int t = threadIdx.x;
  int mi = mask[t];
  int j = mi / F1;
  int k = mi - j * F1;
  ks[t] = k;
  __syncthreads();
  int mykey = (k << 8) | t;
  int rank = 0;
  for (int l2 = 0; l2 < 256; ++l2)
    rank += (((ks[l2] << 8) | l2) < mykey);
  sv[rank]   = (k << 16) | (j << 8) | t;
  skey[rank] = k;
  invperm[t] = rank;                 // original index t -> sorted position
  __syncthreads();
  int isend = (t == 255) || (skey[t] != skey[t + 1]);
  sorted[t] = sv[t] | (isend << 24);
}

// ---------------- K1 v3: forward, 2-level DIF stage A (R9 version) ----------
__global__ __launch_bounds__(256, 4) void k_fwd(const float* __restrict__ x,
                                                const int* __restrict__ sorted,
                                                float2* __restrict__ xm) {
  __shared__ float2 rbuf[128][35];   // [row][k], pad 35
  __shared__ float2 cs32[32];        // (cos,sin)(2*pi*m/32)
  int t = threadIdx.x;
  if (t < 32) cs32[t] = make_float2(TWD[(2 * t) & 63], TWD[(2 * t + 48) & 63]);

  int rl  = t >> 1;
  int par = t & 1;
  size_t row = (size_t)blockIdx.x * 128 + rl;
  const float4* xp = (const float4*)(x + row * 64);

  float f[32];
#pragma unroll
  for (int q = 0; q < 16; ++q) {
    float4 v = xp[q];
    f[2 * q + 0] = par ? v.y : v.x;
    f[2 * q + 1] = par ? v.w : v.z;
  }

  float s1v[16], d1v[16];
#pragma unroll
  for (int m = 0; m < 16; ++m) {
    s1v[m] = f[m] + f[m + 16];
    d1v[m] = f[m] - f[m + 16];
  }
  float s2v[8], d2v[8];
#pragma unroll
  for (int m = 0; m < 8; ++m) {
    s2v[m] = s1v[m] + s1v[m + 8];
    d2v[m] = s1v[m] - s1v[m + 8];
  }
  float mR[17], mI[17];
#pragma unroll
  for (int j = 0; j < 17; ++j) { mR[j] = 0.f; mI[j] = 0.f; }
#pragma unroll
  for (int m = 0; m < 8; ++m) {
#pragma unroll
    for (int tq = 0; tq < 5; ++tq) {
      const int j = 4 * tq;
      const int a = (2 * j * m) & 63;        // compile-time
      const float c  = TWD[a];
      const float sn = TWD[(a + 48) & 63];
      if (c  != 0.0f) mR[j] = fmaf(s2v[m],  c,  mR[j]);
      if (sn != 0.0f) mI[j] = fmaf(s2v[m], -sn, mI[j]);
    }
  }
#pragma unroll
  for (int m = 0; m < 8; ++m) {
#pragma unroll
    for (int tq = 0; tq < 4; ++tq) {
      const int j = 4 * tq + 2;
      const int a = (2 * j * m) & 63;
      const float c  = TWD[a];
      const float sn = TWD[(a + 48) & 63];
      if (c  != 0.0f) mR[j] = fmaf(d2v[m],  c,  mR[j]);
      if (sn != 0.0f) mI[j] = fmaf(d2v[m], -sn, mI[j]);
    }
  }
#pragma unroll
  for (int m = 0; m < 16; ++m) {
#pragma unroll
    for (int r = 0; r < 8; ++r) {
      const int j = 2 * r + 1;
      const int a = (2 * j * m) & 63;
      const float c  = TWD[a];
      const float sn = TWD[(a + 48) & 63];
      if (c  != 0.0f) mR[j] = fmaf(d1v[m],  c,  mR[j]);
      if (sn != 0.0f) mI[j] = fmaf(d1v[m], -sn, mI[j]);
    }
  }

  float oR[17], oI[17];
#pragma unroll
  for (int j = 0; j < 17; ++j) {
    oR[j] = __shfl_xor(mR[j], 1, 64);
    oI[j] = __shfl_xor(mI[j], 1, 64);
  }

  if (par == 0) {
#pragma unroll
    for (int k = 0; k <= 16; ++k) {
      const float wr = TWD[k];
      const float s  = TWD[(k + 48) & 63];
      float XR = mR[k];
      float XI = mI[k];
      if (s  != 0.0f) { XR = fmaf( s, oI[k], XR); XI = fmaf(-s, oR[k], XI); }
      if (wr != 0.0f) { XR = fmaf(wr, oR[k], XR); XI = fmaf(wr, oI[k], XI); }
      rbuf[rl][k] = make_float2(XR, XI);
    }
  } else {
#pragma unroll
    for (int k = 17; k <= 31; ++k) {
      const float wr = TWD[k];
      const float s  = TWD[(k + 48) & 63];
      const int p = 32 - k;
      float XR = oR[p];
      float XI = -oI[p];
      if (s  != 0.0f) { XR = fmaf(-s, mI[p], XR); XI = fmaf(-s, mR[p], XI); }
      if (wr != 0.0f) { XR = fmaf(wr, mR[p], XR); XI = fmaf(-wr, mI[p], XI); }
      rbuf[rl][k] = make_float2(XR, XI);
    }
    rbuf[rl][32] = make_float2(oR[0] - mR[0], 0.0f);
  }
  __syncthreads();

  int e = sorted[t];
  int k = (e >> 16) & 63, j = (e >> 8) & 255, l = e & 255;
  float2 acc[4];
#pragma unroll
  for (int u = 0; u < 4; ++u) acc[u] = make_float2(0.f, 0.f);

#pragma unroll 4
  for (int s0 = 0; s0 < 32; ++s0) {
    float2 cs = cs32[(j * s0) & 31];
#pragma unroll
    for (int u = 0; u < 4; ++u) {
      float2 rv = rbuf[u * 32 + s0][k];
      acc[u].x = fmaf(rv.x, cs.x, fmaf(rv.y,  cs.y, acc[u].x));
      acc[u].y = fmaf(rv.y, cs.x, fmaf(-rv.x, cs.y, acc[u].y));
    }
  }
  size_t ub = (size_t)blockIdx.x * 4;
#pragma unroll
  for (int u = 0; u < 4; ++u)
    xm[(ub + u) * 256 + l] = acc[u];
}

// ---------------- K2 v9: o-split x2 + XCD-chunked swizzle --------------------
// Grid 512 = (h 8, ob 2, lb 32): W partitioned by o (rows 1KB apart -> fetch
// granule untouched); xm re-read x2 is L3-resident (33.5 MB < 256 MB) -> no
// HBM cost. swz=(bid&7)*64+bid>>3 keeps each h on one XCD. Per-(ic,i) inner
// accumulation order identical to v5/v8 -> bit-identical om.
__global__ __launch_bounds__(512, 4) void k_mix(const float2* __restrict__ xm,
                                                const float* __restrict__ wr,
                                                const float* __restrict__ wi,
                                                float2* __restrict__ om) {
  __shared__ float4 Asm4[8][4][33];  // 16.9 KB  [i][p][b]
  __shared__ float4 Wsm4[8][33][4];  // 16.9 KB  [i][oo(pad 33)][p]
  int t = threadIdx.x;
  int swz = (blockIdx.x & 7) * 64 + (blockIdx.x >> 3);   // XCD-chunked
  int h  = swz >> 6;
  int ob = (swz >> 5) & 1;
  int lb = (swz & 31) * 8;

  int w    = t >> 6;        // wave id (0..7) -> 4-o group
  int lane = t & 63;
  int b_lo = lane >> 2;     // 16 values
  int o_lo = lane & 3;      // 4 values

  float4 acc[2][4];
#pragma unroll
  for (int brp = 0; brp < 2; ++brp)
#pragma unroll
    for (int p = 0; p < 4; ++p)
      acc[brp][p] = make_float4(0.f, 0.f, 0.f, 0.f);

  for (int ic = 0; ic < 8; ++ic) {
    __syncthreads();
    // stage A: 1024 float4 chunks: c -> (p, i, b)  (identical to v5)
#pragma unroll
    for (int q = 0; q < 2; ++q) {
      int c = t + 512 * q;
      int p = c & 3, ii = (c >> 2) & 7, b = c >> 5;
      const float4* src = (const float4*)(xm +
          (size_t)(((b * 8 + h) * 64) + ic * 8 + ii) * 256 + lb + 2 * p);
      Asm4[ii][p][b] = *src;
    }
    // stage W (o-half): 512 chunks: c -> (p2, oo, ii)
    {
      int c = t;
      int p2 = c & 1, oo = (c >> 1) & 31, ii = c >> 6;
      size_t gidx = (size_t)((h * 64 + ic * 8 + ii) * 64 + ob * 32 + oo) * 256
                  + lb + p2 * 4;
      float4 vr = *(const float4*)(wr + gidx);
      float4 vi = *(const float4*)(wi + gidx);
      Wsm4[ii][oo][2 * p2 + 0] = make_float4(vr.x, vi.x, vr.y, vi.y);
      Wsm4[ii][oo][2 * p2 + 1] = make_float4(vr.z, vi.z, vr.w, vi.w);
    }
    __syncthreads();
#pragma unroll
    for (int i = 0; i < 8; ++i) {
      float4 av[2][4], wv[4];
#pragma unroll
      for (int brp = 0; brp < 2; ++brp)
#pragma unroll
        for (int p = 0; p < 4; ++p)
          av[brp][p] = Asm4[i][p][brp * 16 + b_lo];   // 16 distinct addrs
#pragma unroll
      for (int p = 0; p < 4; ++p)
        wv[p] = Wsm4[i][w * 4 + o_lo][p];             // 4 distinct addrs
#pragma unroll
      for (int brp = 0; brp < 2; ++brp)
#pragma unroll
        for (int p = 0; p < 4; ++p) {
          float4 A = av[brp][p], W = wv[p];
          float4& C = acc[brp][p];
          C.x = fmaf(A.x, W.x, fmaf(-A.y, W.y, C.x));
          C.y = fmaf(A.x, W.y, fmaf( A.y, W.x, C.y));
          C.z = fmaf(A.z, W.z, fmaf(-A.w, W.w, C.z));
          C.w = fmaf(A.z, W.w, fmaf( A.w, W.z, C.w));
        }
    }
  }
#pragma unroll
  for (int brp = 0; brp < 2; ++brp)
#pragma unroll
    for (int p = 0; p < 4; ++p) {
      int b = brp * 16 + b_lo;
      int o = ob * 32 + w * 4 + o_lo;
      *(float4*)(om + (size_t)(((b * 8 + h) * 64) + o) * 256 + lb + 2 * p)
          = acc[brp][p];
    }
}

// ---------------- K3a: mode sum -> T[k][unit*32+a] (coalesced planes) -------
__global__ __launch_bounds__(256, 4) void k_inv_a(const float2* __restrict__ om,
                                                  const int* __restrict__ sorted,
                                                  const int* __restrict__ invperm,
                                                  float* __restrict__ T) {
  __shared__ float4 om16s[16 * 128];  // 32.8 KB, sorted-order pairs
  __shared__ float2 cs32[32];
  __shared__ int4   smodes4[64];
  int t = threadIdx.x;
  size_t ub = (size_t)blockIdx.x * 16;

  {
    int pos = invperm[t];
    float2* dst = (float2*)om16s;
    const float2* omg = om + ub * 256;
#pragma unroll
    for (int u = 0; u < 16; ++u)
      dst[u * 256 + pos] = omg[u * 256 + t];
  }
  if (t < 32) cs32[t] = make_float2(TWD[(2 * t) & 63], TWD[(2 * t + 48) & 63]);
  if (t < 64) smodes4[t] = ((const int4*)sorted)[t];
  __syncthreads();

  int up = t >> 5;          // unit-pair 0..7
  int a  = t & 31;
  int u0 = up * 2, u1 = u0 + 1;
  float g0 = 0.f, g1 = 0.f;
  long long seen = 0;       // 64-bit: shift by k (0..32) well-defined

#define PROC2(EV, R0, I0, R1, I1)                                             \
  do {                                                                        \
    int e_ = (EV);                                                            \
    int j_ = (e_ >> 8) & 255;                                                 \
    float2 cs_ = cs32[(j_ * a) & 31];                                         \
    g0 = fmaf((R0), cs_.x, g0); g0 = fmaf(-(I0), cs_.y, g0);                  \
    g1 = fmaf((R1), cs_.x, g1); g1 = fmaf(-(I1), cs_.y, g1);                  \
    if (e_ & (1 << 24)) {                                                     \
      int k_ = (e_ >> 16) & 63;                                               \
      seen |= 1ll << k_;                                                      \
      T[(size_t)k_ * NROWS + (ub + u0) * 32 + a] = g0;                        \
      T[(size_t)k_ * NROWS + (ub + u1) * 32 + a] = g1;                        \
      g0 = 0.f; g1 = 0.f;                                                     \
    }                                                                         \
  } while (0)

#pragma unroll 2
  for (int q = 0; q < 64; ++q) {
    int4   ee  = smodes4[q];
    float4 oA0 = om16s[u0 * 128 + 2 * q + 0];
    float4 oB0 = om16s[u0 * 128 + 2 * q + 1];
    float4 oA1 = om16s[u1 * 128 + 2 * q + 0];
    float4 oB1 = om16s[u1 * 128 + 2 * q + 1];
    PROC2(ee.x, oA0.x, oA0.y, oA1.x, oA1.y);
    PROC2(ee.y, oA0.z, oA0.w, oA1.z, oA1.w);
    PROC2(ee.z, oB0.x, oB0.y, oB1.x, oB1.y);
    PROC2(ee.w, oB0.z, oB0.w, oB1.z, oB1.w);
  }
#undef PROC2

#pragma unroll
  for (int k = 0; k < 33; ++k)
    if (!((seen >> k) & 1)) {
      T[(size_t)k * NROWS + (ub + u0) * 32 + a] = 0.f;
      T[(size_t)k * NROWS + (ub + u1) * 32 + a] = 0.f;
    }
}

// ---------------- K3b: exact compile-time cosine constants -------------------
template <int SG>
__device__ __forceinline__ void inv_b_body(const float (*T8)[34], int r,
                                           float* __restrict__ y, size_t Rb) {
  float acc[16];
  {
    float t0 = T8[r][0];
#pragma unroll
    for (int o = 0; o < 16; ++o)
      acc[o] = t0 * (1.0f / 2048.0f);          // k=0: cos=1
  }
#pragma unroll
  for (int k = 1; k < 33; ++k) {
    float tk = T8[r][k];
#pragma unroll
    for (int o = 0; o < 16; ++o) {
      const float C = ((k == 32) ? (1.0f / 2048.0f) : (2.0f / 2048.0f))
                    * TWD[(k * (SG * 16 + o)) & 63];   // compile-time literal
      if (C != 0.0f) acc[o] = fmaf(tk, C, acc[o]);
    }
  }
  float* yp = y + (Rb + r) * 64 + SG * 16;
#pragma unroll
  for (int q = 0; q < 4; ++q)
    *(float4*)(yp + 4 * q) = make_float4(acc[4 * q + 0], acc[4 * q + 1],
                                         acc[4 * q + 2], acc[4 * q + 3]);
}

__global__ __launch_bounds__(256, 4) void k_inv_b(const float* __restrict__ T,
                                                  float* __restrict__ y) {
  __shared__ float T8[64][34];
  int t = threadIdx.x;
  size_t Rb = (size_t)blockIdx.x * 64;

#pragma unroll
  for (int q = 0; q < 9; ++q) {
    int c = t + 256 * q;
    if (c < 2112) {
      int kq = c >> 6, r = c & 63;
      T8[r][kq] = T[(size_t)kq * NROWS + Rb + r];   // coalesced 256B runs
    }
  }
  __syncthreads();

  int wv = t >> 6;          // wave-uniform sg
  int r  = t & 63;
  if      (wv == 0) inv_b_body<0>(T8, r, y, Rb);
  else if (wv == 1) inv_b_body<1>(T8, r, y, Rb);
  else if (wv == 2) inv_b_body<2>(T8, r, y, Rb);
  else              inv_b_body<3>(T8, r, y, Rb);
}

// ---------------- K3 v7 fallback (if ws too small): R9 version --------------
__global__ __launch_bounds__(512, 4) void k_inv(const float2* __restrict__ om,
                                                const int* __restrict__ sorted,
                                                const int* __restrict__ invperm,
                                                float* __restrict__ y) {
  __shared__ float4 om8s[8 * 128];
  __shared__ float  c2s[33][64];
  __shared__ float2 cs32[32];
  __shared__ int4   smodes4[64];
  int t = threadIdx.x;
  size_t ub = (size_t)blockIdx.x * 8;

  {
    int l  = t & 255;
    int u0 = t >> 8;
    int pos = invperm[l];
    float2* dst = (float2*)om8s;
    const float2* omg = om + ub * 256;
#pragma unroll
    for (int q = 0; q < 4; ++q) {
      int u = u0 + 2 * q;
      dst[u * 256 + pos] = omg[u * 256 + l];
    }
  }
#pragma unroll
  for (int q = 0; q < 5; ++q) {
    int idx = t + 512 * q;
    if (idx < 2112) {
      int k = idx >> 6, s1 = idx & 63;
      float w = (k == 0 || k == 32) ? (1.0f / 2048.0f) : (2.0f / 2048.0f);
      c2s[k][s1] = w * TWD[(k * s1) & 63];
    }
  }
  if (t < 32) cs32[t] = make_float2(TWD[(2 * t) & 63], TWD[(2 * t + 48) & 63]);
  if (t < 64) smodes4[t] = ((const int4*)sorted)[t];
  __syncthreads();

  int u    = t >> 6;
  int a    = (t >> 1) & 31;
  int half = t & 1;

  float4 a0 = make_float4(0.f,0.f,0.f,0.f), a1 = a0, a2 = a0, a3 = a0;
  float4 a4 = a0, a5 = a0, a6 = a0, a7 = a0;
  float g = 0.f;

#define SPREAD(KK)                                                            \
  do {                                                                        \
    const float4* crow = (const float4*)&c2s[(KK)][half * 32];                \
    float4 c;                                                                 \
    c = crow[0]; a0.x=fmaf(g,c.x,a0.x); a0.y=fmaf(g,c.y,a0.y); a0.z=fmaf(g,c.z,a0.z); a0.w=fmaf(g,c.w,a0.w); \
    c = crow[1]; a1.x=fmaf(g,c.x,a1.x); a1.y=fmaf(g,c.y,a1.y); a1.z=fmaf(g,c.z,a1.z); a1.w=fmaf(g,c.w,a1.w); \
    c = crow[2]; a2.x=fmaf(g,c.x,a2.x); a2.y=fmaf(g,c.y,a2.y); a2.z=fmaf(g,c.z,a2.z); a2.w=fmaf(g,c.w,a2.w); \
    c = crow[3]; a3.x=fmaf(g,c.x,a3.x); a3.y=fmaf(g,c.y,a3.y); a3.z=fmaf(g,c.z,a3.z); a3.w=fmaf(g,c.w,a3.w); \
    c = crow[4]; a4.x=fmaf(g,c.x,a4.x); a4.y=fmaf(g,c.y,a4.y); a4.z=fmaf(g,c.z,a4.z); a4.w=fmaf(g,c.w,a4.w); \
    c = crow[5]; a5.x=fmaf(g,c.x,a5.x); a5.y=fmaf(g,c.y,a5.y); a5.z=fmaf(g,c.z,a5.z); a5.w=fmaf(g,c.w,a5.w); \
    c = crow[6]; a6.x=fmaf(g,c.x,a6.x); a6.y=fmaf(g,c.y,a6.y); a6.z=fmaf(g,c.z,a6.z); a6.w=fmaf(g,c.w,a6.w); \
    c = crow[7]; a7.x=fmaf(g,c.x,a7.x); a7.y=fmaf(g,c.y,a7.y); a7.z=fmaf(g,c.z,a7.z); a7.w=fmaf(g,c.w,a7.w); \
    g = 0.f;                                                                  \
  } while (0)

#define PROC(EV, OVR, OVI)                                                    \
  do {                                                                        \
    int e_ = (EV);                                                            \
    int j_ = (e_ >> 8) & 255;                                                 \
    float2 cs_ = cs32[(j_ * a) & 31];                                         \
    g = fmaf((OVR), cs_.x, g);                                                \
    g = fmaf(-(OVI), cs_.y, g);                                               \
    if (e_ & (1 << 24)) SPREAD((e_ >> 16) & 63);                              \
  } while (0)

#pragma unroll 2
  for (int q = 0; q < 64; ++q) {
    int4   ee = smodes4[q];
    float4 oA = om8s[u * 128 + 2 * q + 0];
    float4 oB = om8s[u * 128 + 2 * q + 1];
    PROC(ee.x, oA.x, oA.y);
    PROC(ee.y, oA.z, oA.w);
    PROC(ee.z, oB.x, oB.y);
    PROC(ee.w, oB.z, oB.w);
  }
#undef PROC
#undef SPREAD

  float4* yp = (float4*)(y + (ub + u) * 2048 + a * 64 + half * 32);
  yp[0] = a0; yp[1] = a1; yp[2] = a2; yp[3] = a3;
  yp[4] = a4; yp[5] = a5; yp[6] = a6; yp[7] = a7;
}

extern "C" void kernel_launch(void* const* d_in, const int* in_sizes, int n_in,
                              void* d_out, int out_size, void* d_ws, size_t ws_size,
                              hipStream_t stream) {
  const float* x    = (const float*)d_in[0];
  const float* wre  = (const float*)d_in[1];
  const float* wim  = (const float*)d_in[2];
  const int*   mask = (const int*)d_in[3];

  float*  y  = (float*)d_out;
  float2* xm = (float2*)d_out;                        // scratch: dead before y written
  char* base = (char*)d_ws;
  float2* omp   = (float2*)d_ws;                      // 33.55 MB
  int*  sorted  = (int*)(base + 33554432);            // 1 KB (16B-aligned)
  int*  invperm = (int*)(base + 33555456);            // 1 KB
  float* T      = (float*)(base + 33556480);          // 69.2 MB (if available)
  const size_t ws_needed = 33556480ull + (size_t)33 * NROWS * 4;

  k_sort<<<1, 256, 0, stream>>>(mask, sorted, invperm);
  k_fwd <<<4096, 256, 0, stream>>>(x, sorted, xm);
  k_mix <<<512, 512, 0, stream>>>(xm, wre, wim, omp);
  if (ws_size >= ws_needed) {
    k_inv_a<<<1024, 256, 0, stream>>>(omp, sorted, invperm, T);
    k_inv_b<<<8192, 256, 0, stream>>>(T, y);
  } else {
    k_inv<<<2048, 512, 0, stream>>>(omp, sorted, invperm, y);
  }
}

// Round 21
// 203.137 us; speedup vs baseline: 1.3213x; 1.0139x over previous
//
#include <hip/hip_runtime.h>

#define F1 33

// cos(2*pi*m/64); sin(2*pi*m/64) = TWD[(m+48)&63]
constexpr float TWD[64] = {
   1.00000000f,  0.99518473f,  0.98078528f,  0.95694034f,
   0.92387953f,  0.88192126f,  0.83146961f,  0.77301045f,
   0.70710678f,  0.63439328f,  0.55557023f,  0.47139674f,
   0.38268343f,  0.29028468f,  0.19509032f,  0.09801714f,
   0.00000000f, -0.09801714f, -0.19509032f, -0.29028468f,
  -0.38268343f, -0.47139674f, -0.55557023f, -0.63439328f,
  -0.70710678f, -0.77301045f, -0.83146961f, -0.88192126f,
  -0.92387953f, -0.95694034f, -0.98078528f, -0.99518473f,
  -1.00000000f, -0.99518473f, -0.98078528f, -0.95694034f,
  -0.92387953f, -0.88192126f, -0.83146961f, -0.77301045f,
  -0.70710678f, -0.63439328f, -0.55557023f, -0.47139674f,
  -0.38268343f, -0.29028468f, -0.19509032f, -0.09801714f,
   0.00000000f,  0.09801714f,  0.19509032f,  0.29028468f,
   0.38268343f,  0.47139674f,  0.55557023f,  0.63439328f,
   0.70710678f,  0.77301045f,  0.83146961f,  0.88192126f,
   0.92387953f,  0.95694034f,  0.98078528f,  0.99518473f,
};

#define NROWS 524288   // 16384 units * 32 a-rows

// ------- K0: sort modes by k (tie: original l); bit24 = run-end; invperm ----
__global__ __launch_bounds__(256) void k_sort(const int* __restrict__ mask,
                                              int* __restrict__ sorted,
                                              int* __restrict__ invperm) {
  __shared__ int ks[256];
  __shared__ int sv[256];
  __shared__ int skey[256];
  int t = threadIdx.x;
  int mi = mask[t];
  int j = mi / F1;
  int k = mi - j * F1;
  ks[t] = k;
  __syncthreads();
  int mykey = (k << 8) | t;
  int rank = 0;
  for (int l2 = 0; l2 < 256; ++l2)
    rank += (((ks[l2] << 8) | l2) < mykey);
  sv[rank]   = (k << 16) | (j << 8) | t;
  skey[rank] = k;
  invperm[t] = rank;                 // original index t -> sorted position
  __syncthreads();
  int isend = (t == 255) || (skey[t] != skey[t + 1]);
  sorted[t] = sv[t] | (isend << 24);
}

// ---------------- K1 v4: DIF stage A + unit-contiguous rbuf_t ----------------
// rbuf_t[k][s0*4+u]: one b128 read = 2 units -> stage-B DS reads halve
// (128 b64 -> 64 b128). FMA order per (s0,u) identical -> bit-identical xm.
__global__ __launch_bounds__(256, 4) void k_fwd(const float* __restrict__ x,
                                                const int* __restrict__ sorted,
                                                float2* __restrict__ xm) {
  __shared__ float2 rbuf_t[33][132];  // [k][s0*4+u], pad 132 (34.8 KB)
  __shared__ float2 cs32[32];         // (cos,sin)(2*pi*m/32)
  int t = threadIdx.x;
  if (t < 32) cs32[t] = make_float2(TWD[(2 * t) & 63], TWD[(2 * t + 48) & 63]);

  int rl  = t >> 1;
  int par = t & 1;
  int prow = (rl & 31) * 4 + (rl >> 5);   // unit-innermost permuted row
  size_t row = (size_t)blockIdx.x * 128 + rl;
  const float4* xp = (const float4*)(x + row * 64);

  float f[32];
#pragma unroll
  for (int q = 0; q < 16; ++q) {
    float4 v = xp[q];
    f[2 * q + 0] = par ? v.y : v.x;
    f[2 * q + 1] = par ? v.w : v.z;
  }

  float s1v[16], d1v[16];
#pragma unroll
  for (int m = 0; m < 16; ++m) {
    s1v[m] = f[m] + f[m + 16];
    d1v[m] = f[m] - f[m + 16];
  }
  float s2v[8], d2v[8];
#pragma unroll
  for (int m = 0; m < 8; ++m) {
    s2v[m] = s1v[m] + s1v[m + 8];
    d2v[m] = s1v[m] - s1v[m + 8];
  }
  float mR[17], mI[17];
#pragma unroll
  for (int j = 0; j < 17; ++j) { mR[j] = 0.f; mI[j] = 0.f; }
#pragma unroll
  for (int m = 0; m < 8; ++m) {
#pragma unroll
    for (int tq = 0; tq < 5; ++tq) {
      const int j = 4 * tq;
      const int a = (2 * j * m) & 63;        // compile-time
      const float c  = TWD[a];
      const float sn = TWD[(a + 48) & 63];
      if (c  != 0.0f) mR[j] = fmaf(s2v[m],  c,  mR[j]);
      if (sn != 0.0f) mI[j] = fmaf(s2v[m], -sn, mI[j]);
    }
  }
#pragma unroll
  for (int m = 0; m < 8; ++m) {
#pragma unroll
    for (int tq = 0; tq < 4; ++tq) {
      const int j = 4 * tq + 2;
      const int a = (2 * j * m) & 63;
      const float c  = TWD[a];
      const float sn = TWD[(a + 48) & 63];
      if (c  != 0.0f) mR[j] = fmaf(d2v[m],  c,  mR[j]);
      if (sn != 0.0f) mI[j] = fmaf(d2v[m], -sn, mI[j]);
    }
  }
#pragma unroll
  for (int m = 0; m < 16; ++m) {
#pragma unroll
    for (int r = 0; r < 8; ++r) {
      const int j = 2 * r + 1;
      const int a = (2 * j * m) & 63;
      const float c  = TWD[a];
      const float sn = TWD[(a + 48) & 63];
      if (c  != 0.0f) mR[j] = fmaf(d1v[m],  c,  mR[j]);
      if (sn != 0.0f) mI[j] = fmaf(d1v[m], -sn, mI[j]);
    }
  }

  float oR[17], oI[17];
#pragma unroll
  for (int j = 0; j < 17; ++j) {
    oR[j] = __shfl_xor(mR[j], 1, 64);
    oI[j] = __shfl_xor(mI[j], 1, 64);
  }

  if (par == 0) {
#pragma unroll
    for (int k = 0; k <= 16; ++k) {
      const float wr = TWD[k];
      const float s  = TWD[(k + 48) & 63];
      float XR = mR[k];
      float XI = mI[k];
      if (s  != 0.0f) { XR = fmaf( s, oI[k], XR); XI = fmaf(-s, oR[k], XI); }
      if (wr != 0.0f) { XR = fmaf(wr, oR[k], XR); XI = fmaf(wr, oI[k], XI); }
      rbuf_t[k][prow] = make_float2(XR, XI);
    }
  } else {
#pragma unroll
    for (int k = 17; k <= 31; ++k) {
      const float wr = TWD[k];
      const float s  = TWD[(k + 48) & 63];
      const int p = 32 - k;
      float XR = oR[p];
      float XI = -oI[p];
      if (s  != 0.0f) { XR = fmaf(-s, mI[p], XR); XI = fmaf(-s, mR[p], XI); }
      if (wr != 0.0f) { XR = fmaf(wr, mR[p], XR); XI = fmaf(-wr, mI[p], XI); }
      rbuf_t[k][prow] = make_float2(XR, XI);
    }
    rbuf_t[32][prow] = make_float2(oR[0] - mR[0], 0.0f);
  }
  __syncthreads();

  int e = sorted[t];
  int k = (e >> 16) & 63, j = (e >> 8) & 255, l = e & 255;
  float2 acc[4];
#pragma unroll
  for (int u = 0; u < 4; ++u) acc[u] = make_float2(0.f, 0.f);

#pragma unroll 4
  for (int s0 = 0; s0 < 32; ++s0) {
    float2 cs = cs32[(j * s0) & 31];
    float4 vA = *(const float4*)&rbuf_t[k][s0 * 4 + 0];   // units 0,1
    float4 vB = *(const float4*)&rbuf_t[k][s0 * 4 + 2];   // units 2,3
    acc[0].x = fmaf(vA.x, cs.x, fmaf(vA.y,  cs.y, acc[0].x));
    acc[0].y = fmaf(vA.y, cs.x, fmaf(-vA.x, cs.y, acc[0].y));
    acc[1].x = fmaf(vA.z, cs.x, fmaf(vA.w,  cs.y, acc[1].x));
    acc[1].y = fmaf(vA.w, cs.x, fmaf(-vA.z, cs.y, acc[1].y));
    acc[2].x = fmaf(vB.x, cs.x, fmaf(vB.y,  cs.y, acc[2].x));
    acc[2].y = fmaf(vB.y, cs.x, fmaf(-vB.x, cs.y, acc[2].y));
    acc[3].x = fmaf(vB.z, cs.x, fmaf(vB.w,  cs.y, acc[3].x));
    acc[3].y = fmaf(vB.w, cs.x, fmaf(-vB.z, cs.y, acc[3].y));
  }
  size_t ub = (size_t)blockIdx.x * 4;
#pragma unroll
  for (int u = 0; u < 4; ++u)
    xm[(ub + u) * 256 + l] = acc[u];
}

// ---------------- K2 v9: o-split x2 + XCD-chunked swizzle --------------------
__global__ __launch_bounds__(512, 4) void k_mix(const float2* __restrict__ xm,
                                                const float* __restrict__ wr,
                                                const float* __restrict__ wi,
                                                float2* __restrict__ om) {
  __shared__ float4 Asm4[8][4][33];  // 16.9 KB  [i][p][b]
  __shared__ float4 Wsm4[8][33][4];  // 16.9 KB  [i][oo(pad 33)][p]
  int t = threadIdx.x;
  int swz = (blockIdx.x & 7) * 64 + (blockIdx.x >> 3);   // XCD-chunked
  int h  = swz >> 6;
  int ob = (swz >> 5) & 1;
  int lb = (swz & 31) * 8;

  int w    = t >> 6;        // wave id (0..7) -> 4-o group
  int lane = t & 63;
  int b_lo = lane >> 2;     // 16 values
  int o_lo = lane & 3;      // 4 values

  float4 acc[2][4];
#pragma unroll
  for (int brp = 0; brp < 2; ++brp)
#pragma unroll
    for (int p = 0; p < 4; ++p)
      acc[brp][p] = make_float4(0.f, 0.f, 0.f, 0.f);

  for (int ic = 0; ic < 8; ++ic) {
    __syncthreads();
#pragma unroll
    for (int q = 0; q < 2; ++q) {
      int c = t + 512 * q;
      int p = c & 3, ii = (c >> 2) & 7, b = c >> 5;
      const float4* src = (const float4*)(xm +
          (size_t)(((b * 8 + h) * 64) + ic * 8 + ii) * 256 + lb + 2 * p);
      Asm4[ii][p][b] = *src;
    }
    {
      int c = t;
      int p2 = c & 1, oo = (c >> 1) & 31, ii = c >> 6;
      size_t gidx = (size_t)((h * 64 + ic * 8 + ii) * 64 + ob * 32 + oo) * 256
                  + lb + p2 * 4;
      float4 vr = *(const float4*)(wr + gidx);
      float4 vi = *(const float4*)(wi + gidx);
      Wsm4[ii][oo][2 * p2 + 0] = make_float4(vr.x, vi.x, vr.y, vi.y);
      Wsm4[ii][oo][2 * p2 + 1] = make_float4(vr.z, vi.z, vr.w, vi.w);
    }
    __syncthreads();
#pragma unroll
    for (int i = 0; i < 8; ++i) {
      float4 av[2][4], wv[4];
#pragma unroll
      for (int brp = 0; brp < 2; ++brp)
#pragma unroll
        for (int p = 0; p < 4; ++p)
          av[brp][p] = Asm4[i][p][brp * 16 + b_lo];   // 16 distinct addrs
#pragma unroll
      for (int p = 0; p < 4; ++p)
        wv[p] = Wsm4[i][w * 4 + o_lo][p];             // 4 distinct addrs
#pragma unroll
      for (int brp = 0; brp < 2; ++brp)
#pragma unroll
        for (int p = 0; p < 4; ++p) {
          float4 A = av[brp][p], W = wv[p];
          float4& C = acc[brp][p];
          C.x = fmaf(A.x, W.x, fmaf(-A.y, W.y, C.x));
          C.y = fmaf(A.x, W.y, fmaf( A.y, W.x, C.y));
          C.z = fmaf(A.z, W.z, fmaf(-A.w, W.w, C.z));
          C.w = fmaf(A.z, W.w, fmaf( A.w, W.z, C.w));
        }
    }
  }
#pragma unroll
  for (int brp = 0; brp < 2; ++brp)
#pragma unroll
    for (int p = 0; p < 4; ++p) {
      int b = brp * 16 + b_lo;
      int o = ob * 32 + w * 4 + o_lo;
      *(float4*)(om + (size_t)(((b * 8 + h) * 64) + o) * 256 + lb + 2 * p)
          = acc[brp][p];
    }
}

// ---------------- K3a: mode sum -> T[k][unit*32+a] (coalesced planes) -------
__global__ __launch_bounds__(256, 4) void k_inv_a(const float2* __restrict__ om,
                                                  const int* __restrict__ sorted,
                                                  const int* __restrict__ invperm,
                                                  float* __restrict__ T) {
  __shared__ float4 om16s[16 * 128];  // 32.8 KB, sorted-order pairs
  __shared__ float2 cs32[32];
  __shared__ int4   smodes4[64];
  int t = threadIdx.x;
  size_t ub = (size_t)blockIdx.x * 16;

  {
    int pos = invperm[t];
    float2* dst = (float2*)om16s;
    const float2* omg = om + ub * 256;
#pragma unroll
    for (int u = 0; u < 16; ++u)
      dst[u * 256 + pos] = omg[u * 256 + t];
  }
  if (t < 32) cs32[t] = make_float2(TWD[(2 * t) & 63], TWD[(2 * t + 48) & 63]);
  if (t < 64) smodes4[t] = ((const int4*)sorted)[t];
  __syncthreads();

  int up = t >> 5;          // unit-pair 0..7
  int a  = t & 31;
  int u0 = up * 2, u1 = u0 + 1;
  float g0 = 0.f, g1 = 0.f;
  long long seen = 0;       // 64-bit: shift by k (0..32) well-defined

#define PROC2(EV, R0, I0, R1, I1)                                             \
  do {                                                                        \
    int e_ = (EV);                                                            \
    int j_ = (e_ >> 8) & 255;                                                 \
    float2 cs_ = cs32[(j_ * a) & 31];                                         \
    g0 = fmaf((R0), cs_.x, g0); g0 = fmaf(-(I0), cs_.y, g0);                  \
    g1 = fmaf((R1), cs_.x, g1); g1 = fmaf(-(I1), cs_.y, g1);                  \
    if (e_ & (1 << 24)) {                                                     \
      int k_ = (e_ >> 16) & 63;                                               \
      seen |= 1ll << k_;                                                      \
      T[(size_t)k_ * NROWS + (ub + u0) * 32 + a] = g0;                        \
      T[(size_t)k_ * NROWS + (ub + u1) * 32 + a] = g1;                        \
      g0 = 0.f; g1 = 0.f;                                                     \
    }                                                                         \
  } while (0)

#pragma unroll 2
  for (int q = 0; q < 64; ++q) {
    int4   ee  = smodes4[q];
    float4 oA0 = om16s[u0 * 128 + 2 * q + 0];
    float4 oB0 = om16s[u0 * 128 + 2 * q + 1];
    float4 oA1 = om16s[u1 * 128 + 2 * q + 0];
    float4 oB1 = om16s[u1 * 128 + 2 * q + 1];
    PROC2(ee.x, oA0.x, oA0.y, oA1.x, oA1.y);
    PROC2(ee.y, oA0.z, oA0.w, oA1.z, oA1.w);
    PROC2(ee.z, oB0.x, oB0.y, oB1.x, oB1.y);
    PROC2(ee.w, oB0.z, oB0.w, oB1.z, oB1.w);
  }
#undef PROC2

#pragma unroll
  for (int k = 0; k < 33; ++k)
    if (!((seen >> k) & 1)) {
      T[(size_t)k * NROWS + (ub + u0) * 32 + a] = 0.f;
      T[(size_t)k * NROWS + (ub + u1) * 32 + a] = 0.f;
    }
}

// ---------------- K3b: exact compile-time cosine constants -------------------
template <int SG>
__device__ __forceinline__ void inv_b_body(const float (*T8)[34], int r,
                                           float* __restrict__ y, size_t Rb) {
  float acc[16];
  {
    float t0 = T8[r][0];
#pragma unroll
    for (int o = 0; o < 16; ++o)
      acc[o] = t0 * (1.0f / 2048.0f);          // k=0: cos=1
  }
#pragma unroll
  for (int k = 1; k < 33; ++k) {
    float tk = T8[r][k];
#pragma unroll
    for (int o = 0; o < 16; ++o) {
      const float C = ((k == 32) ? (1.0f / 2048.0f) : (2.0f / 2048.0f))
                    * TWD[(k * (SG * 16 + o)) & 63];   // compile-time literal
      if (C != 0.0f) acc[o] = fmaf(tk, C, acc[o]);
    }
  }
  float* yp = y + (Rb + r) * 64 + SG * 16;
#pragma unroll
  for (int q = 0; q < 4; ++q)
    *(float4*)(yp + 4 * q) = make_float4(acc[4 * q + 0], acc[4 * q + 1],
                                         acc[4 * q + 2], acc[4 * q + 3]);
}

__global__ __launch_bounds__(256, 4) void k_inv_b(const float* __restrict__ T,
                                                  float* __restrict__ y) {
  __shared__ float T8[64][34];
  int t = threadIdx.x;
  size_t Rb = (size_t)blockIdx.x * 64;

#pragma unroll
  for (int q = 0; q < 9; ++q) {
    int c = t + 256 * q;
    if (c < 2112) {
      int kq = c >> 6, r = c & 63;
      T8[r][kq] = T[(size_t)kq * NROWS + Rb + r];   // coalesced 256B runs
    }
  }
  __syncthreads();

  int wv = t >> 6;          // wave-uniform sg
  int r  = t & 63;
  if      (wv == 0) inv_b_body<0>(T8, r, y, Rb);
  else if (wv == 1) inv_b_body<1>(T8, r, y, Rb);
  else if (wv == 2) inv_b_body<2>(T8, r, y, Rb);
  else              inv_b_body<3>(T8, r, y, Rb);
}

// ---------------- K3 v7 fallback (if ws too small): R9 version --------------
__global__ __launch_bounds__(512, 4) void k_inv(const float2* __restrict__ om,
                                                const int* __restrict__ sorted,
                                                const int* __restrict__ invperm,
                                                float* __restrict__ y) {
  __shared__ float4 om8s[8 * 128];
  __shared__ float  c2s[33][64];
  __shared__ float2 cs32[32];
  __shared__ int4   smodes4[64];
  int t = threadIdx.x;
  size_t ub = (size_t)blockIdx.x * 8;

  {
    int l  = t & 255;
    int u0 = t >> 8;
    int pos = invperm[l];
    float2* dst = (float2*)om8s;
    const float2* omg = om + ub * 256;
#pragma unroll
    for (int q = 0; q < 4; ++q) {
      int u = u0 + 2 * q;
      dst[u * 256 + pos] = omg[u * 256 + l];
    }
  }
#pragma unroll
  for (int q = 0; q < 5; ++q) {
    int idx = t + 512 * q;
    if (idx < 2112) {
      int k = idx >> 6, s1 = idx & 63;
      float w = (k == 0 || k == 32) ? (1.0f / 2048.0f) : (2.0f / 2048.0f);
      c2s[k][s1] = w * TWD[(k * s1) & 63];
    }
  }
  if (t < 32) cs32[t] = make_float2(TWD[(2 * t) & 63], TWD[(2 * t + 48) & 63]);
  if (t < 64) smodes4[t] = ((const int4*)sorted)[t];
  __syncthreads();

  int u    = t >> 6;
  int a    = (t >> 1) & 31;
  int half = t & 1;

  float4 a0 = make_float4(0.f,0.f,0.f,0.f), a1 = a0, a2 = a0, a3 = a0;
  float4 a4 = a0, a5 = a0, a6 = a0, a7 = a0;
  float g = 0.f;

#define SPREAD(KK)                                                            \
  do {                                                                        \
    const float4* crow = (const float4*)&c2s[(KK)][half * 32];                \
    float4 c;                                                                 \
    c = crow[0]; a0.x=fmaf(g,c.x,a0.x); a0.y=fmaf(g,c.y,a0.y); a0.z=fmaf(g,c.z,a0.z); a0.w=fmaf(g,c.w,a0.w); \
    c = crow[1]; a1.x=fmaf(g,c.x,a1.x); a1.y=fmaf(g,c.y,a1.y); a1.z=fmaf(g,c.z,a1.z); a1.w=fmaf(g,c.w,a1.w); \
    c = crow[2]; a2.x=fmaf(g,c.x,a2.x); a2.y=fmaf(g,c.y,a2.y); a2.z=fmaf(g,c.z,a2.z); a2.w=fmaf(g,c.w,a2.w); \
    c = crow[3]; a3.x=fmaf(g,c.x,a3.x); a3.y=fmaf(g,c.y,a3.y); a3.z=fmaf(g,c.z,a3.z); a3.w=fmaf(g,c.w,a3.w); \
    c = crow[4]; a4.x=fmaf(g,c.x,a4.x); a4.y=fmaf(g,c.y,a4.y); a4.z=fmaf(g,c.z,a4.z); a4.w=fmaf(g,c.w,a4.w); \
    c = crow[5]; a5.x=fmaf(g,c.x,a5.x); a5.y=fmaf(g,c.y,a5.y); a5.z=fmaf(g,c.z,a5.z); a5.w=fmaf(g,c.w,a5.w); \
    c = crow[6]; a6.x=fmaf(g,c.x,a6.x); a6.y=fmaf(g,c.y,a6.y); a6.z=fmaf(g,c.z,a6.z); a6.w=fmaf(g,c.w,a6.w); \
    c = crow[7]; a7.x=fmaf(g,c.x,a7.x); a7.y=fmaf(g,c.y,a7.y); a7.z=fmaf(g,c.z,a7.z); a7.w=fmaf(g,c.w,a7.w); \
    g = 0.f;                                                                  \
  } while (0)

#define PROC(EV, OVR, OVI)                                                    \
  do {                                                                        \
    int e_ = (EV);                                                            \
    int j_ = (e_ >> 8) & 255;                                                 \
    float2 cs_ = cs32[(j_ * a) & 31];                                         \
    g = fmaf((OVR), cs_.x, g);                                                \
    g = fmaf(-(OVI), cs_.y, g);                                               \
    if (e_ & (1 << 24)) SPREAD((e_ >> 16) & 63);                              \
  } while (0)

#pragma unroll 2
  for (int q = 0; q < 64; ++q) {
    int4   ee = smodes4[q];
    float4 oA = om8s[u * 128 + 2 * q + 0];
    float4 oB = om8s[u * 128 + 2 * q + 1];
    PROC(ee.x, oA.x, oA.y);
    PROC(ee.y, oA.z, oA.w);
    PROC(ee.z, oB.x, oB.y);
    PROC(ee.w, oB.z, oB.w);
  }
#undef PROC
#undef SPREAD

  float4* yp = (float4*)(y + (ub + u) * 2048 + a * 64 + half * 32);
  yp[0] = a0; yp[1] = a1; yp[2] = a2; yp[3] = a3;
  yp[4] = a4; yp[5] = a5; yp[6] = a6; yp[7] = a7;
}

extern "C" void kernel_launch(void* const* d_in, const int* in_sizes, int n_in,
                              void* d_out, int out_size, void* d_ws, size_t ws_size,
                              hipStream_t stream) {
  const float* x    = (const float*)d_in[0];
  const float* wre  = (const float*)d_in[1];
  const float* wim  = (const float*)d_in[2];
  const int*   mask = (const int*)d_in[3];

  float*  y  = (float*)d_out;
  float2* xm = (float2*)d_out;                        // scratch: dead before y written
  char* base = (char*)d_ws;
  float2* omp   = (float2*)d_ws;                      // 33.55 MB
  int*  sorted  = (int*)(base + 33554432);            // 1 KB (16B-aligned)
  int*  invperm = (int*)(base + 33555456);            // 1 KB
  float* T      = (float*)(base + 33556480);          // 69.2 MB (if available)
  const size_t ws_needed = 33556480ull + (size_t)33 * NROWS * 4;

  k_sort<<<1, 256, 0, stream>>>(mask, sorted, invperm);
  k_fwd <<<4096, 256, 0, stream>>>(x, sorted, xm);
  k_mix <<<512, 512, 0, stream>>>(xm, wre, wim, omp);
  if (ws_size >= ws_needed) {
    k_inv_a<<<1024, 256, 0, stream>>>(omp, sorted, invperm, T);
    k_inv_b<<<8192, 256, 0, stream>>>(T, y);
  } else {
    k_inv<<<2048, 512, 0, stream>>>(omp, sorted, invperm, y);
  }
}